// Round 2
// 181.434 us; speedup vs baseline: 1.1038x; 1.1038x over previous
//
#include <hip/hip_runtime.h>
#include <math.h>

#define T_SEQ 2048
#define D_MODEL 1024
#define NH 16
#define HD 64

typedef unsigned short ushort_t;
typedef unsigned int uint_t;
typedef short short8 __attribute__((ext_vector_type(8)));
typedef float floatx4 __attribute__((ext_vector_type(4)));

// ---- bf16 helpers (RNE) ----
__device__ __forceinline__ ushort_t f2bf(float f) {
    uint_t u = __float_as_uint(f);
    u += 0x7FFFu + ((u >> 16) & 1u);
    return (ushort_t)(u >> 16);
}
__device__ __forceinline__ uint_t pack2(float a, float b) {
    return (uint_t)f2bf(a) | ((uint_t)f2bf(b) << 16);
}
// copy 16 bf16 (32B) global/LDS
__device__ __forceinline__ void cp16(ushort_t* dst, const ushort_t* src) {
    uint4 a = ((const uint4*)src)[0];
    uint4 b = ((const uint4*)src)[1];
    ((uint4*)dst)[0] = a;
    ((uint4*)dst)[1] = b;
}

#define LDB 72    // GEMM LDS row stride (ushorts): 64 + 8 pad (16B-aligned, 2-way max)
#define LDK 72    // attn K/Q/P row stride (64 cols)
#define LDV 136   // attn V row stride (128 cols + 8 pad)

// ---------------------------------------------------------------------------
// Kernel 0: one-time fp32 -> bf16 convert of x, Wq, Wk, Wv, Wp.
// ---------------------------------------------------------------------------
__global__ __launch_bounds__(256) void to_bf16(
        const float* __restrict__ x,  const float* __restrict__ wq,
        const float* __restrict__ wk, const float* __restrict__ wv,
        const float* __restrict__ wp,
        ushort_t* __restrict__ xb,  ushort_t* __restrict__ wqb,
        ushort_t* __restrict__ wkb, ushort_t* __restrict__ wvb,
        ushort_t* __restrict__ wpb)
{
    size_t i = (size_t)blockIdx.x * 256 + threadIdx.x;
    const float* src; ushort_t* dst; size_t off;
    if (i < 262144)      { src = x;  dst = xb;  off = i; }
    else if (i < 393216) { src = wq; dst = wqb; off = i - 262144; }
    else if (i < 524288) { src = wk; dst = wkb; off = i - 393216; }
    else if (i < 655360) { src = wv; dst = wvb; off = i - 524288; }
    else                 { src = wp; dst = wpb; off = i - 655360; }
    float4 f0 = ((const float4*)src)[off * 2];
    float4 f1 = ((const float4*)src)[off * 2 + 1];
    uint4 u;
    u.x = pack2(f0.x, f0.y); u.y = pack2(f0.z, f0.w);
    u.z = pack2(f1.x, f1.y); u.w = pack2(f1.z, f1.w);
    ((uint4*)dst)[off] = u;
}

// ---------------------------------------------------------------------------
// Kernel 1: QKV GEMM (bf16 MFMA, BK=64) with FUSED RMSNorm+RoPE epilogue.
// ---------------------------------------------------------------------------
__global__ __launch_bounds__(256) void gemm_qkv(
        const ushort_t* __restrict__ xb,
        const ushort_t* __restrict__ Wqb, const ushort_t* __restrict__ Wkb,
        const ushort_t* __restrict__ Wvb,
        const float* __restrict__ vi, const float* __restrict__ lam,
        ushort_t* __restrict__ qb, ushort_t* __restrict__ kb,
        ushort_t* __restrict__ vbt)
{
    const int z = blockIdx.z;
    const ushort_t* __restrict__ W = (z == 0) ? Wqb : (z == 1) ? Wkb : Wvb;
    const int row0 = blockIdx.y * 128;
    const int col0 = blockIdx.x * 128;

    __shared__ ushort_t As[128 * LDB];
    __shared__ ushort_t Bs[128 * LDB];

    const int tid = threadIdx.x;
    const int wave = tid >> 6, lane = tid & 63;
    const int wm = wave >> 1, wn = wave & 1;
    const int l15 = lane & 15, quad = lane >> 4;
    const int r_st = tid >> 1;            // staging row 0..127
    const int c_st = (tid & 1) * 32;      // staging col 0/32

    floatx4 acc[4][4];
    #pragma unroll
    for (int i = 0; i < 4; ++i)
        #pragma unroll
        for (int j = 0; j < 4; ++j)
            acc[i][j] = (floatx4){0.f, 0.f, 0.f, 0.f};

    for (int k0 = 0; k0 < D_MODEL; k0 += 64) {
        __syncthreads();
        cp16(As + r_st * LDB + c_st,      xb + (size_t)(row0 + r_st) * D_MODEL + k0 + c_st);
        cp16(As + r_st * LDB + c_st + 16, xb + (size_t)(row0 + r_st) * D_MODEL + k0 + c_st + 16);
        cp16(Bs + r_st * LDB + c_st,      W  + (size_t)(col0 + r_st) * D_MODEL + k0 + c_st);
        cp16(Bs + r_st * LDB + c_st + 16, W  + (size_t)(col0 + r_st) * D_MODEL + k0 + c_st + 16);
        __syncthreads();
        #pragma unroll
        for (int kh = 0; kh < 2; ++kh) {
            short8 a[4], b[4];
            #pragma unroll
            for (int i = 0; i < 4; ++i) {
                a[i] = *(const short8*)(As + (64 * wm + i * 16 + l15) * LDB + kh * 32 + quad * 8);
                b[i] = *(const short8*)(Bs + (64 * wn + i * 16 + l15) * LDB + kh * 32 + quad * 8);
            }
            #pragma unroll
            for (int i = 0; i < 4; ++i)
                #pragma unroll
                for (int j = 0; j < 4; ++j)
                    acc[i][j] = __builtin_amdgcn_mfma_f32_16x16x32_bf16(a[i], b[j], acc[i][j], 0, 0, 0);
        }
    }

    if (z < 2) {
        ushort_t* __restrict__ o = (z == 0) ? qb : kb;
        const float oscale = (z == 0) ? 0.125f : 1.0f;   // fold 1/sqrt(hd) into q
        const int hbase = col0 + 64 * wn;
        const float eps = 1.1920929e-7f;
        const float fr = exp2f(-10.0f * (float)l15 / 15.0f);  // rotating-pair freq
        #pragma unroll
        for (int i = 0; i < 4; ++i)
            #pragma unroll
            for (int r = 0; r < 4; ++r) {
                const int t = row0 + 64 * wm + i * 16 + quad * 4 + r;
                float v0 = acc[i][0][r], v1 = acc[i][1][r];
                float v2 = acc[i][2][r], v3 = acc[i][3][r];
                float ss = v0 * v0 + v1 * v1 + v2 * v2 + v3 * v3;
                ss += __shfl_xor(ss, 1);
                ss += __shfl_xor(ss, 2);
                ss += __shfl_xor(ss, 4);
                ss += __shfl_xor(ss, 8);
                const float sc = rsqrtf(ss * (1.0f / 64.0f) + eps);
                v0 *= sc; v1 *= sc; v2 *= sc; v3 *= sc;
                const float th = (float)t * fr;
                const float cs = cosf(th), sn = sinf(th);
                const float y0 = v0 * cs + v2 * sn;   // shown-source rotary sign
                const float y2 = v2 * cs - v0 * sn;
                const size_t rb = (size_t)t * D_MODEL + hbase;
                o[rb +  0 + l15] = f2bf(y0 * oscale);
                o[rb + 16 + l15] = f2bf(v1 * oscale);
                o[rb + 32 + l15] = f2bf(y2 * oscale);
                o[rb + 48 + l15] = f2bf(v3 * oscale);
            }
    } else {
        const float l0 = lam[0], l1 = lam[1];
        #pragma unroll
        for (int i = 0; i < 4; ++i)
            #pragma unroll
            for (int j = 0; j < 4; ++j) {
                const int tb = row0 + 64 * wm + i * 16 + quad * 4;
                const int jj = col0 + 64 * wn + j * 16 + l15;
                float b0 = l0 * acc[i][j][0] + l1 * vi[(size_t)(tb + 0) * D_MODEL + jj];
                float b1 = l0 * acc[i][j][1] + l1 * vi[(size_t)(tb + 1) * D_MODEL + jj];
                float b2 = l0 * acc[i][j][2] + l1 * vi[(size_t)(tb + 2) * D_MODEL + jj];
                float b3 = l0 * acc[i][j][3] + l1 * vi[(size_t)(tb + 3) * D_MODEL + jj];
                uint2 u;
                u.x = pack2(b0, b1);
                u.y = pack2(b2, b3);
                *(uint2*)(vbt + (size_t)jj * T_SEQ + tb) = u;   // [d][t]
            }
    }
}

// ---------------------------------------------------------------------------
// Kernel 2: MFMA flash attention, KV-SPLIT two-phase.
// Work decomposition per head:
//   x in [ 0,16): qt = 16+x,   KV tiles [0, mid)      -> fp32 partial (chunk 0)
//   x in [16,32): qt = 47-x,   KV tiles [mid, qt+1)   -> fp32 partial (chunk 1)
//   x in [32,48): qt = 47-x,   KV tiles [0, qt+1)     -> direct bf16 write
// mid = (qt+2)/2 so the two chunks are ~balanced (8..16 sub-tiles each).
// 768 blocks total (was 512), per-block work in [1,16] sub-tiles (was [1,32]).
// Partials: unnormalized O (fp32) + per-row (m,l) to workspace; combined by
// attn_combine. Softmax/MFMA body identical to the verified single-pass kernel.
// ---------------------------------------------------------------------------
__global__ __launch_bounds__(256) void attn(
        const ushort_t* __restrict__ qb, const ushort_t* __restrict__ kb,
        const ushort_t* __restrict__ vbt, ushort_t* __restrict__ yb,
        float* __restrict__ Opart, float* __restrict__ MLpart)
{
    const int h = blockIdx.y;
    const int x = blockIdx.x;
    int qt, ct_begin, ct_end, pidx;
    if (x < 16) {                       // chunk 0 of qt>=16 (dense, no mask hit)
        qt = 16 + x;
        const int mid = (qt + 2) >> 1;
        ct_begin = 0; ct_end = mid;
        pidx = ((h * 16 + x) << 1);
    } else if (x < 32) {                // chunk 1 of qt>=16 (contains diagonal)
        qt = 47 - x;
        const int mid = (qt + 2) >> 1;
        ct_begin = mid; ct_end = qt + 1;
        pidx = ((h * 16 + (qt - 16)) << 1) + 1;
    } else {                            // direct, qt in [0,15]
        qt = 47 - x;
        ct_begin = 0; ct_end = qt + 1;
        pidx = -1;
    }
    const int t0 = qt * 64;

    __shared__ ushort_t Ks[128 * LDK];   // [s_local 0..127][d]
    __shared__ ushort_t Vs[64 * LDV];    // [d][s_local 0..127]
    __shared__ ushort_t QPs[64 * LDK];   // Q tile, then reused for P

    const int tid = threadIdx.x;
    const int wave = tid >> 6, lane = tid & 63;
    const int l15 = lane & 15, quad = lane >> 4;

    // stage Q (64x64)
    {
        const int r4 = tid >> 2, c4 = (tid & 3) * 16;
        cp16(QPs + r4 * LDK + c4, qb + (size_t)(t0 + r4) * D_MODEL + h * HD + c4);
    }
    __syncthreads();
    short8 qf[2];
    qf[0] = *(const short8*)(QPs + (16 * wave + l15) * LDK + 0  + quad * 8);
    qf[1] = *(const short8*)(QPs + (16 * wave + l15) * LDK + 32 + quad * 8);

    float m_run[4], l_run[4];
    floatx4 O[4];
    #pragma unroll
    for (int r = 0; r < 4; ++r) { m_run[r] = -1e30f; l_run[r] = 0.0f; }
    #pragma unroll
    for (int d = 0; d < 4; ++d) O[d] = (floatx4){0.f, 0.f, 0.f, 0.f};

    for (int kt0 = ct_begin; kt0 < ct_end; kt0 += 2) {
        const int s0 = kt0 * 64;
        __syncthreads();
        {   // stage K: 128 rows x 64 cols
            const int r2 = tid >> 1, c2 = (tid & 1) * 32;
            cp16(Ks + r2 * LDK + c2,      kb + (size_t)(s0 + r2) * D_MODEL + h * HD + c2);
            cp16(Ks + r2 * LDK + c2 + 16, kb + (size_t)(s0 + r2) * D_MODEL + h * HD + c2 + 16);
            // stage V: 64 rows (d) x 128 cols (s)
            const int r4 = tid >> 2, c4 = (tid & 3) * 32;
            cp16(Vs + r4 * LDV + c4,      vbt + (size_t)(h * HD + r4) * T_SEQ + s0 + c4);
            cp16(Vs + r4 * LDV + c4 + 16, vbt + (size_t)(h * HD + r4) * T_SEQ + s0 + c4 + 16);
        }
        __syncthreads();

        const int ktend = (kt0 + 1 < ct_end) ? 2 : 1;
        for (int sub = 0; sub < ktend; ++sub) {
            const int kt = kt0 + sub;
            const int sl = sub * 64;             // local s offset in LDS

            floatx4 sa[4];
            #pragma unroll
            for (int ct = 0; ct < 4; ++ct) {
                short8 b0 = *(const short8*)(Ks + (sl + ct * 16 + l15) * LDK + 0  + quad * 8);
                short8 b1 = *(const short8*)(Ks + (sl + ct * 16 + l15) * LDK + 32 + quad * 8);
                floatx4 t4 = (floatx4){0.f, 0.f, 0.f, 0.f};
                t4 = __builtin_amdgcn_mfma_f32_16x16x32_bf16(qf[0], b0, t4, 0, 0, 0);
                t4 = __builtin_amdgcn_mfma_f32_16x16x32_bf16(qf[1], b1, t4, 0, 0, 0);
                sa[ct] = t4;
            }
            if (kt == qt) {   // causal mask on the diagonal tile
                #pragma unroll
                for (int ct = 0; ct < 4; ++ct)
                    #pragma unroll
                    for (int r = 0; r < 4; ++r) {
                        int trow = 16 * wave + quad * 4 + r;
                        int scol = ct * 16 + l15;
                        if (scol > trow) sa[ct][r] = -1e30f;
                    }
            }
            // register online-softmax
            float alpha[4], rs[4];
            #pragma unroll
            for (int r = 0; r < 4; ++r) {
                float m0 = fmaxf(fmaxf(sa[0][r], sa[1][r]), fmaxf(sa[2][r], sa[3][r]));
                m0 = fmaxf(m0, __shfl_xor(m0, 1));
                m0 = fmaxf(m0, __shfl_xor(m0, 2));
                m0 = fmaxf(m0, __shfl_xor(m0, 4));
                m0 = fmaxf(m0, __shfl_xor(m0, 8));
                float mn = fmaxf(m_run[r], m0);
                alpha[r] = __expf(m_run[r] - mn);
                m_run[r] = mn;
                rs[r] = 0.0f;
            }
            float p[4][4];
            #pragma unroll
            for (int ct = 0; ct < 4; ++ct)
                #pragma unroll
                for (int r = 0; r < 4; ++r) {
                    p[ct][r] = __expf(sa[ct][r] - m_run[r]);
                    rs[r] += p[ct][r];
                }
            #pragma unroll
            for (int r = 0; r < 4; ++r) {
                rs[r] += __shfl_xor(rs[r], 1);
                rs[r] += __shfl_xor(rs[r], 2);
                rs[r] += __shfl_xor(rs[r], 4);
                rs[r] += __shfl_xor(rs[r], 8);
                l_run[r] = l_run[r] * alpha[r] + rs[r];
            }
            #pragma unroll
            for (int d = 0; d < 4; ++d)
                #pragma unroll
                for (int r = 0; r < 4; ++r) O[d][r] *= alpha[r];

            // P -> LDS (wave-private 16-row stripe; no barrier needed)
            #pragma unroll
            for (int ct = 0; ct < 4; ++ct)
                #pragma unroll
                for (int r = 0; r < 4; ++r)
                    QPs[(16 * wave + quad * 4 + r) * LDK + ct * 16 + l15] = f2bf(p[ct][r]);

            short8 pa0 = *(const short8*)(QPs + (16 * wave + l15) * LDK + 0  + quad * 8);
            short8 pa1 = *(const short8*)(QPs + (16 * wave + l15) * LDK + 32 + quad * 8);
            #pragma unroll
            for (int dt = 0; dt < 4; ++dt) {
                short8 vb0 = *(const short8*)(Vs + (dt * 16 + l15) * LDV + sl + 0  + quad * 8);
                short8 vb1 = *(const short8*)(Vs + (dt * 16 + l15) * LDV + sl + 32 + quad * 8);
                O[dt] = __builtin_amdgcn_mfma_f32_16x16x32_bf16(pa0, vb0, O[dt], 0, 0, 0);
                O[dt] = __builtin_amdgcn_mfma_f32_16x16x32_bf16(pa1, vb1, O[dt], 0, 0, 0);
            }
        }
    }

    if (pidx < 0) {
        // direct: normalize and write bf16
        #pragma unroll
        for (int r = 0; r < 4; ++r) {
            const float inv_l = 1.0f / l_run[r];
            const int t = t0 + 16 * wave + quad * 4 + r;
            #pragma unroll
            for (int dt = 0; dt < 4; ++dt)
                yb[(size_t)t * D_MODEL + h * HD + dt * 16 + l15] = f2bf(O[dt][r] * inv_l);
        }
    } else {
        // partial: unnormalized fp32 O + per-row (m,l)
        float* __restrict__ Op = Opart + (size_t)pidx * 4096;
        #pragma unroll
        for (int r = 0; r < 4; ++r) {
            const int row = 16 * wave + quad * 4 + r;
            #pragma unroll
            for (int dt = 0; dt < 4; ++dt)
                Op[row * 64 + dt * 16 + l15] = O[dt][r];
            if (l15 == 0) {
                MLpart[((size_t)pidx * 64 + row) * 2 + 0] = m_run[r];
                MLpart[((size_t)pidx * 64 + row) * 2 + 1] = l_run[r];
            }
        }
    }
}

// ---------------------------------------------------------------------------
// Kernel 2b: combine the two KV-chunk partials for qt in [16,32).
// grid=(16 qtp, 16 h), block=256. Thread = one (row, 16-col segment).
// ---------------------------------------------------------------------------
__global__ __launch_bounds__(256) void attn_combine(
        const float* __restrict__ Opart, const float* __restrict__ MLpart,
        ushort_t* __restrict__ yb)
{
    const int qtp = blockIdx.x;          // qt = 16 + qtp
    const int h   = blockIdx.y;
    const int tid = threadIdx.x;
    const int row  = tid >> 2;           // 0..63
    const int dseg = (tid & 3) * 16;     // 0/16/32/48
    const int p0 = (h * 16 + qtp) * 2;

    const float m0 = MLpart[((size_t)p0 * 64 + row) * 2 + 0];
    const float l0 = MLpart[((size_t)p0 * 64 + row) * 2 + 1];
    const float m1 = MLpart[(((size_t)p0 + 1) * 64 + row) * 2 + 0];
    const float l1 = MLpart[(((size_t)p0 + 1) * 64 + row) * 2 + 1];
    const float M  = fmaxf(m0, m1);
    const float w0 = __expf(m0 - M), w1 = __expf(m1 - M);
    const float inv = 1.0f / (l0 * w0 + l1 * w1);

    const float* O0 = Opart + (size_t)p0 * 4096 + row * 64 + dseg;
    const float* O1 = O0 + 4096;

    uint_t u[8];
    #pragma unroll
    for (int g = 0; g < 4; ++g) {
        float4 a = ((const float4*)O0)[g];
        float4 b = ((const float4*)O1)[g];
        float y0 = (a.x * w0 + b.x * w1) * inv;
        float y1 = (a.y * w0 + b.y * w1) * inv;
        float y2 = (a.z * w0 + b.z * w1) * inv;
        float y3 = (a.w * w0 + b.w * w1) * inv;
        u[g * 2 + 0] = pack2(y0, y1);
        u[g * 2 + 1] = pack2(y2, y3);
    }
    const int t = (16 + qtp) * 64 + row;
    uint4* dst = (uint4*)(yb + (size_t)t * D_MODEL + h * HD + dseg);
    dst[0] = make_uint4(u[0], u[1], u[2], u[3]);
    dst[1] = make_uint4(u[4], u[5], u[6], u[7]);
}

// ---------------------------------------------------------------------------
// Kernel 3: output projection (bf16 MFMA, BK=64), fp32 out. grid=(8,16).
// ---------------------------------------------------------------------------
__global__ __launch_bounds__(256) void gemm_proj(
        const ushort_t* __restrict__ yb, const ushort_t* __restrict__ Wpb,
        float* __restrict__ out)
{
    const int row0 = blockIdx.y * 128;
    const int col0 = blockIdx.x * 128;

    __shared__ ushort_t As[128 * LDB];
    __shared__ ushort_t Bs[128 * LDB];

    const int tid = threadIdx.x;
    const int wave = tid >> 6, lane = tid & 63;
    const int wm = wave >> 1, wn = wave & 1;
    const int l15 = lane & 15, quad = lane >> 4;
    const int r_st = tid >> 1;
    const int c_st = (tid & 1) * 32;

    floatx4 acc[4][4];
    #pragma unroll
    for (int i = 0; i < 4; ++i)
        #pragma unroll
        for (int j = 0; j < 4; ++j)
            acc[i][j] = (floatx4){0.f, 0.f, 0.f, 0.f};

    for (int k0 = 0; k0 < D_MODEL; k0 += 64) {
        __syncthreads();
        cp16(As + r_st * LDB + c_st,      yb  + (size_t)(row0 + r_st) * D_MODEL + k0 + c_st);
        cp16(As + r_st * LDB + c_st + 16, yb  + (size_t)(row0 + r_st) * D_MODEL + k0 + c_st + 16);
        cp16(Bs + r_st * LDB + c_st,      Wpb + (size_t)(col0 + r_st) * D_MODEL + k0 + c_st);
        cp16(Bs + r_st * LDB + c_st + 16, Wpb + (size_t)(col0 + r_st) * D_MODEL + k0 + c_st + 16);
        __syncthreads();
        #pragma unroll
        for (int kh = 0; kh < 2; ++kh) {
            short8 a[4], b[4];
            #pragma unroll
            for (int i = 0; i < 4; ++i) {
                a[i] = *(const short8*)(As + (64 * wm + i * 16 + l15) * LDB + kh * 32 + quad * 8);
                b[i] = *(const short8*)(Bs + (64 * wn + i * 16 + l15) * LDB + kh * 32 + quad * 8);
            }
            #pragma unroll
            for (int i = 0; i < 4; ++i)
                #pragma unroll
                for (int j = 0; j < 4; ++j)
                    acc[i][j] = __builtin_amdgcn_mfma_f32_16x16x32_bf16(a[i], b[j], acc[i][j], 0, 0, 0);
        }
    }

    #pragma unroll
    for (int i = 0; i < 4; ++i)
        #pragma unroll
        for (int j = 0; j < 4; ++j) {
            const int t = row0 + 64 * wm + i * 16 + quad * 4;
            const int jj = col0 + 64 * wn + j * 16 + l15;
            #pragma unroll
            for (int r = 0; r < 4; ++r)
                out[(size_t)(t + r) * D_MODEL + jj] = acc[i][j][r];
        }
}

// ---------------------------------------------------------------------------
extern "C" void kernel_launch(void* const* d_in, const int* in_sizes, int n_in,
                              void* d_out, int out_size, void* d_ws, size_t ws_size,
                              hipStream_t stream) {
    (void)in_sizes; (void)n_in; (void)out_size; (void)ws_size;
    const float* x   = (const float*)d_in[0];
    const float* vi  = (const float*)d_in[1];
    const float* Wq  = (const float*)d_in[2];
    const float* Wk  = (const float*)d_in[3];
    const float* Wv  = (const float*)d_in[4];
    const float* Wp  = (const float*)d_in[5];
    const float* lam = (const float*)d_in[6];

    char* base = (char*)d_ws;                                  // 28 MiB used
    ushort_t* xb  = (ushort_t*)(base);                         // [ 0, 4) MiB (dead after gemm_qkv)
    ushort_t* wqb = (ushort_t*)(base + (size_t)4  * 1048576);  // [ 4, 6)  (dead after gemm_qkv)
    ushort_t* wkb = (ushort_t*)(base + (size_t)6  * 1048576);  // [ 6, 8)  (dead after gemm_qkv)
    ushort_t* wvb = (ushort_t*)(base + (size_t)8  * 1048576);  // [ 8,10)  (dead after gemm_qkv)
    ushort_t* wpb = (ushort_t*)(base + (size_t)10 * 1048576);  // [10,12)  (live until gemm_proj)
    ushort_t* qb  = (ushort_t*)(base + (size_t)12 * 1048576);  // [12,16)
    ushort_t* kb  = (ushort_t*)(base + (size_t)16 * 1048576);  // [16,20)
    ushort_t* vbt = (ushort_t*)(base + (size_t)20 * 1048576);  // [20,24)  [d][t]
    ushort_t* yb  = (ushort_t*)(base + (size_t)24 * 1048576);  // [24,28)
    // attn partials reuse [0, 8.25) MiB — dead xb/wqb/wkb/wvb space:
    float* Opart  = (float*)(base);                            // 512 * 4096 * 4B = 8 MiB
    float* MLpart = (float*)(base + (size_t)8 * 1048576);      // 512 * 64 * 2 * 4B = 256 KiB
    float* out = (float*)d_out;

    to_bf16<<<dim3(786432 / 256), 256, 0, stream>>>(x, Wq, Wk, Wv, Wp, xb, wqb, wkb, wvb, wpb);
    gemm_qkv<<<dim3(8, 16, 3), 256, 0, stream>>>(xb, wqb, wkb, wvb, vi, lam, qb, kb, vbt);
    attn<<<dim3(48, 16), 256, 0, stream>>>(qb, kb, vbt, yb, Opart, MLpart);
    attn_combine<<<dim3(16, 16), 256, 0, stream>>>(Opart, MLpart, yb);
    gemm_proj<<<dim3(8, 16), 256, 0, stream>>>(yb, wpb, out);
}

// Round 3
// 170.659 us; speedup vs baseline: 1.1735x; 1.0631x over previous
//
#include <hip/hip_runtime.h>
#include <math.h>

#define T_SEQ 2048
#define D_MODEL 1024
#define NH 16
#define HD 64

typedef unsigned short ushort_t;
typedef unsigned int uint_t;
typedef short short8 __attribute__((ext_vector_type(8)));
typedef float floatx4 __attribute__((ext_vector_type(4)));

// ---- bf16 helpers (RNE) ----
__device__ __forceinline__ ushort_t f2bf(float f) {
    uint_t u = __float_as_uint(f);
    u += 0x7FFFu + ((u >> 16) & 1u);
    return (ushort_t)(u >> 16);
}
__device__ __forceinline__ uint_t pack2(float a, float b) {
    return (uint_t)f2bf(a) | ((uint_t)f2bf(b) << 16);
}
// copy 16 bf16 (32B) global/LDS
__device__ __forceinline__ void cp16(ushort_t* dst, const ushort_t* src) {
    uint4 a = ((const uint4*)src)[0];
    uint4 b = ((const uint4*)src)[1];
    ((uint4*)dst)[0] = a;
    ((uint4*)dst)[1] = b;
}

#define LDB 72    // GEMM LDS row stride (ushorts): 64 + 8 pad (16B-aligned, 2-way max)
#define LDK 72    // attn K/Q/P/V row stride (64 cols + 8 pad)

// ---------------------------------------------------------------------------
// Kernel 0: one-time fp32 -> bf16 convert of x, Wq, Wk, Wv, Wp.
// ---------------------------------------------------------------------------
__global__ __launch_bounds__(256) void to_bf16(
        const float* __restrict__ x,  const float* __restrict__ wq,
        const float* __restrict__ wk, const float* __restrict__ wv,
        const float* __restrict__ wp,
        ushort_t* __restrict__ xb,  ushort_t* __restrict__ wqb,
        ushort_t* __restrict__ wkb, ushort_t* __restrict__ wvb,
        ushort_t* __restrict__ wpb)
{
    size_t i = (size_t)blockIdx.x * 256 + threadIdx.x;
    const float* src; ushort_t* dst; size_t off;
    if (i < 262144)      { src = x;  dst = xb;  off = i; }
    else if (i < 393216) { src = wq; dst = wqb; off = i - 262144; }
    else if (i < 524288) { src = wk; dst = wkb; off = i - 393216; }
    else if (i < 655360) { src = wv; dst = wvb; off = i - 524288; }
    else                 { src = wp; dst = wpb; off = i - 655360; }
    float4 f0 = ((const float4*)src)[off * 2];
    float4 f1 = ((const float4*)src)[off * 2 + 1];
    uint4 u;
    u.x = pack2(f0.x, f0.y); u.y = pack2(f0.z, f0.w);
    u.z = pack2(f1.x, f1.y); u.w = pack2(f1.z, f1.w);
    ((uint4*)dst)[off] = u;
}

// ---------------------------------------------------------------------------
// Kernel 1: QKV GEMM (bf16 MFMA, BK=64) with FUSED RMSNorm+RoPE epilogue.
// ---------------------------------------------------------------------------
__global__ __launch_bounds__(256) void gemm_qkv(
        const ushort_t* __restrict__ xb,
        const ushort_t* __restrict__ Wqb, const ushort_t* __restrict__ Wkb,
        const ushort_t* __restrict__ Wvb,
        const float* __restrict__ vi, const float* __restrict__ lam,
        ushort_t* __restrict__ qb, ushort_t* __restrict__ kb,
        ushort_t* __restrict__ vbt)
{
    const int z = blockIdx.z;
    const ushort_t* __restrict__ W = (z == 0) ? Wqb : (z == 1) ? Wkb : Wvb;
    const int row0 = blockIdx.y * 128;
    const int col0 = blockIdx.x * 128;

    __shared__ ushort_t As[128 * LDB];
    __shared__ ushort_t Bs[128 * LDB];

    const int tid = threadIdx.x;
    const int wave = tid >> 6, lane = tid & 63;
    const int wm = wave >> 1, wn = wave & 1;
    const int l15 = lane & 15, quad = lane >> 4;
    const int r_st = tid >> 1;            // staging row 0..127
    const int c_st = (tid & 1) * 32;      // staging col 0/32

    floatx4 acc[4][4];
    #pragma unroll
    for (int i = 0; i < 4; ++i)
        #pragma unroll
        for (int j = 0; j < 4; ++j)
            acc[i][j] = (floatx4){0.f, 0.f, 0.f, 0.f};

    for (int k0 = 0; k0 < D_MODEL; k0 += 64) {
        __syncthreads();
        cp16(As + r_st * LDB + c_st,      xb + (size_t)(row0 + r_st) * D_MODEL + k0 + c_st);
        cp16(As + r_st * LDB + c_st + 16, xb + (size_t)(row0 + r_st) * D_MODEL + k0 + c_st + 16);
        cp16(Bs + r_st * LDB + c_st,      W  + (size_t)(col0 + r_st) * D_MODEL + k0 + c_st);
        cp16(Bs + r_st * LDB + c_st + 16, W  + (size_t)(col0 + r_st) * D_MODEL + k0 + c_st + 16);
        __syncthreads();
        #pragma unroll
        for (int kh = 0; kh < 2; ++kh) {
            short8 a[4], b[4];
            #pragma unroll
            for (int i = 0; i < 4; ++i) {
                a[i] = *(const short8*)(As + (64 * wm + i * 16 + l15) * LDB + kh * 32 + quad * 8);
                b[i] = *(const short8*)(Bs + (64 * wn + i * 16 + l15) * LDB + kh * 32 + quad * 8);
            }
            #pragma unroll
            for (int i = 0; i < 4; ++i)
                #pragma unroll
                for (int j = 0; j < 4; ++j)
                    acc[i][j] = __builtin_amdgcn_mfma_f32_16x16x32_bf16(a[i], b[j], acc[i][j], 0, 0, 0);
        }
    }

    if (z < 2) {
        ushort_t* __restrict__ o = (z == 0) ? qb : kb;
        const float oscale = (z == 0) ? 0.125f : 1.0f;   // fold 1/sqrt(hd) into q
        const int hbase = col0 + 64 * wn;
        const float eps = 1.1920929e-7f;
        const float fr = exp2f(-10.0f * (float)l15 / 15.0f);  // rotating-pair freq
        #pragma unroll
        for (int i = 0; i < 4; ++i)
            #pragma unroll
            for (int r = 0; r < 4; ++r) {
                const int t = row0 + 64 * wm + i * 16 + quad * 4 + r;
                float v0 = acc[i][0][r], v1 = acc[i][1][r];
                float v2 = acc[i][2][r], v3 = acc[i][3][r];
                float ss = v0 * v0 + v1 * v1 + v2 * v2 + v3 * v3;
                ss += __shfl_xor(ss, 1);
                ss += __shfl_xor(ss, 2);
                ss += __shfl_xor(ss, 4);
                ss += __shfl_xor(ss, 8);
                const float sc = rsqrtf(ss * (1.0f / 64.0f) + eps);
                v0 *= sc; v1 *= sc; v2 *= sc; v3 *= sc;
                const float th = (float)t * fr;
                const float cs = cosf(th), sn = sinf(th);
                const float y0 = v0 * cs + v2 * sn;   // shown-source rotary sign
                const float y2 = v2 * cs - v0 * sn;
                const size_t rb = (size_t)t * D_MODEL + hbase;
                o[rb +  0 + l15] = f2bf(y0 * oscale);
                o[rb + 16 + l15] = f2bf(v1 * oscale);
                o[rb + 32 + l15] = f2bf(y2 * oscale);
                o[rb + 48 + l15] = f2bf(v3 * oscale);
            }
    } else {
        const float l0 = lam[0], l1 = lam[1];
        #pragma unroll
        for (int i = 0; i < 4; ++i)
            #pragma unroll
            for (int j = 0; j < 4; ++j) {
                const int tb = row0 + 64 * wm + i * 16 + quad * 4;
                const int jj = col0 + 64 * wn + j * 16 + l15;
                float b0 = l0 * acc[i][j][0] + l1 * vi[(size_t)(tb + 0) * D_MODEL + jj];
                float b1 = l0 * acc[i][j][1] + l1 * vi[(size_t)(tb + 1) * D_MODEL + jj];
                float b2 = l0 * acc[i][j][2] + l1 * vi[(size_t)(tb + 2) * D_MODEL + jj];
                float b3 = l0 * acc[i][j][3] + l1 * vi[(size_t)(tb + 3) * D_MODEL + jj];
                uint2 u;
                u.x = pack2(b0, b1);
                u.y = pack2(b2, b3);
                *(uint2*)(vbt + (size_t)jj * T_SEQ + tb) = u;   // [d][t]
            }
    }
}

// ---------------------------------------------------------------------------
// Kernel 2: MFMA flash attention, KV-split, FIXED-MAX softmax.
// Scores are provably bounded: RMSNorm => ||q||=||k||=8, rotary preserves
// norm, 1/8 folded into q  =>  |s| <= 8 (+bf16 eps). So softmax uses a
// CONSTANT max m=8: p = exp(s-8) <= ~1.06. No per-tile max reduce, no sum
// shuffle (per-lane l accumulator, reduced once at the end), no O rescale.
// LDS: Ks/Vs/QPs each [64][72] = 27648 B total -> 5 blocks/CU (was 3).
// Work split per head (big-first):
//   x in [ 0,16): qt = 31-x,  KV [0, mid)     -> fp32 partial chunk 0
//   x in [16,32): qt = 47-x,  KV [mid, qt+1)  -> fp32 partial chunk 1 (diag)
//   x in [32,48): qt = 47-x,  KV [0, qt+1)    -> direct bf16 write
// ---------------------------------------------------------------------------
__global__ __launch_bounds__(256) void attn(
        const ushort_t* __restrict__ qb, const ushort_t* __restrict__ kb,
        const ushort_t* __restrict__ vbt, ushort_t* __restrict__ yb,
        float* __restrict__ Opart, float* __restrict__ Lpart)
{
    const int h = blockIdx.y;
    const int x = blockIdx.x;
    int qt, ct_begin, ct_end, pidx;
    if (x < 16) {                       // chunk 0 of qt>=16 (dense, no mask hit)
        qt = 31 - x;
        const int mid = (qt + 2) >> 1;
        ct_begin = 0; ct_end = mid;
        pidx = ((h * 16 + (qt - 16)) << 1);
    } else if (x < 32) {                // chunk 1 of qt>=16 (contains diagonal)
        qt = 47 - x;
        const int mid = (qt + 2) >> 1;
        ct_begin = mid; ct_end = qt + 1;
        pidx = ((h * 16 + (qt - 16)) << 1) + 1;
    } else {                            // direct, qt in [0,15]
        qt = 47 - x;
        ct_begin = 0; ct_end = qt + 1;
        pidx = -1;
    }
    const int t0 = qt * 64;

    __shared__ ushort_t Ks[64 * LDK];    // [s_local][d]
    __shared__ ushort_t Vs[64 * LDK];    // [d][s_local]
    __shared__ ushort_t QPs[64 * LDK];   // Q tile, then reused for P

    const int tid = threadIdx.x;
    const int wave = tid >> 6, lane = tid & 63;
    const int l15 = lane & 15, quad = lane >> 4;
    const int r4 = tid >> 2, c4 = (tid & 3) * 16;   // staging: 1 cp16/thread

    // stage Q (64x64)
    cp16(QPs + r4 * LDK + c4, qb + (size_t)(t0 + r4) * D_MODEL + h * HD + c4);
    __syncthreads();
    short8 qf[2];
    qf[0] = *(const short8*)(QPs + (16 * wave + l15) * LDK + 0  + quad * 8);
    qf[1] = *(const short8*)(QPs + (16 * wave + l15) * LDK + 32 + quad * 8);

    float l_acc[4];
    floatx4 O[4];
    #pragma unroll
    for (int r = 0; r < 4; ++r) l_acc[r] = 0.0f;
    #pragma unroll
    for (int d = 0; d < 4; ++d) O[d] = (floatx4){0.f, 0.f, 0.f, 0.f};

    for (int kt = ct_begin; kt < ct_end; ++kt) {
        const int s0 = kt * 64;
        __syncthreads();
        // stage K: 64 s-rows x 64 d-cols; V: 64 d-rows x 64 s-cols
        cp16(Ks + r4 * LDK + c4, kb  + (size_t)(s0 + r4) * D_MODEL + h * HD + c4);
        cp16(Vs + r4 * LDK + c4, vbt + (size_t)(h * HD + r4) * T_SEQ + s0 + c4);
        __syncthreads();

        floatx4 sa[4];
        #pragma unroll
        for (int ct = 0; ct < 4; ++ct) {
            short8 b0 = *(const short8*)(Ks + (ct * 16 + l15) * LDK + 0  + quad * 8);
            short8 b1 = *(const short8*)(Ks + (ct * 16 + l15) * LDK + 32 + quad * 8);
            floatx4 t4 = (floatx4){0.f, 0.f, 0.f, 0.f};
            t4 = __builtin_amdgcn_mfma_f32_16x16x32_bf16(qf[0], b0, t4, 0, 0, 0);
            t4 = __builtin_amdgcn_mfma_f32_16x16x32_bf16(qf[1], b1, t4, 0, 0, 0);
            sa[ct] = t4;
        }
        if (kt == qt) {   // causal mask on the diagonal tile
            #pragma unroll
            for (int ct = 0; ct < 4; ++ct)
                #pragma unroll
                for (int r = 0; r < 4; ++r) {
                    int trow = 16 * wave + quad * 4 + r;
                    int scol = ct * 16 + l15;
                    if (scol > trow) sa[ct][r] = -1e30f;
                }
        }
        // fixed-max softmax: p = exp(s - 8), per-lane l accumulation only
        float p[4][4];
        #pragma unroll
        for (int ct = 0; ct < 4; ++ct)
            #pragma unroll
            for (int r = 0; r < 4; ++r) {
                p[ct][r] = __expf(sa[ct][r] - 8.0f);
                l_acc[r] += p[ct][r];
            }

        // P -> LDS (wave-private 16-row stripe; no barrier needed)
        #pragma unroll
        for (int ct = 0; ct < 4; ++ct)
            #pragma unroll
            for (int r = 0; r < 4; ++r)
                QPs[(16 * wave + quad * 4 + r) * LDK + ct * 16 + l15] = f2bf(p[ct][r]);

        short8 pa0 = *(const short8*)(QPs + (16 * wave + l15) * LDK + 0  + quad * 8);
        short8 pa1 = *(const short8*)(QPs + (16 * wave + l15) * LDK + 32 + quad * 8);
        #pragma unroll
        for (int dt = 0; dt < 4; ++dt) {
            short8 vb0 = *(const short8*)(Vs + (dt * 16 + l15) * LDK + 0  + quad * 8);
            short8 vb1 = *(const short8*)(Vs + (dt * 16 + l15) * LDK + 32 + quad * 8);
            O[dt] = __builtin_amdgcn_mfma_f32_16x16x32_bf16(pa0, vb0, O[dt], 0, 0, 0);
            O[dt] = __builtin_amdgcn_mfma_f32_16x16x32_bf16(pa1, vb1, O[dt], 0, 0, 0);
        }
    }

    // one-time row-sum reduce across the 16 col-lanes
    float l_run[4];
    #pragma unroll
    for (int r = 0; r < 4; ++r) {
        float s = l_acc[r];
        s += __shfl_xor(s, 1);
        s += __shfl_xor(s, 2);
        s += __shfl_xor(s, 4);
        s += __shfl_xor(s, 8);
        l_run[r] = s;
    }

    if (pidx < 0) {
        // direct: normalize and write bf16
        #pragma unroll
        for (int r = 0; r < 4; ++r) {
            const float inv_l = 1.0f / l_run[r];
            const int t = t0 + 16 * wave + quad * 4 + r;
            #pragma unroll
            for (int dt = 0; dt < 4; ++dt)
                yb[(size_t)t * D_MODEL + h * HD + dt * 16 + l15] = f2bf(O[dt][r] * inv_l);
        }
    } else {
        // partial: unnormalized fp32 O + per-row l (fixed max => no m needed)
        float* __restrict__ Op = Opart + (size_t)pidx * 4096;
        #pragma unroll
        for (int r = 0; r < 4; ++r) {
            const int row = 16 * wave + quad * 4 + r;
            #pragma unroll
            for (int dt = 0; dt < 4; ++dt)
                Op[row * 64 + dt * 16 + l15] = O[dt][r];
            if (l15 == 0) Lpart[(size_t)pidx * 64 + row] = l_run[r];
        }
    }
}

// ---------------------------------------------------------------------------
// Kernel 2b: combine the two KV-chunk partials for qt in [16,32).
// Fixed max on both chunks => combined = (O0 + O1) / (l0 + l1).
// grid=(16 qtp, 16 h), block=256. Thread = one (row, 16-col segment).
// ---------------------------------------------------------------------------
__global__ __launch_bounds__(256) void attn_combine(
        const float* __restrict__ Opart, const float* __restrict__ Lpart,
        ushort_t* __restrict__ yb)
{
    const int qtp = blockIdx.x;          // qt = 16 + qtp
    const int h   = blockIdx.y;
    const int tid = threadIdx.x;
    const int row  = tid >> 2;           // 0..63
    const int dseg = (tid & 3) * 16;     // 0/16/32/48
    const int p0 = (h * 16 + qtp) * 2;

    const float l0 = Lpart[(size_t)p0 * 64 + row];
    const float l1 = Lpart[((size_t)p0 + 1) * 64 + row];
    const float inv = 1.0f / (l0 + l1);

    const float* O0 = Opart + (size_t)p0 * 4096 + row * 64 + dseg;
    const float* O1 = O0 + 4096;

    uint_t u[8];
    #pragma unroll
    for (int g = 0; g < 4; ++g) {
        float4 a = ((const float4*)O0)[g];
        float4 b = ((const float4*)O1)[g];
        u[g * 2 + 0] = pack2((a.x + b.x) * inv, (a.y + b.y) * inv);
        u[g * 2 + 1] = pack2((a.z + b.z) * inv, (a.w + b.w) * inv);
    }
    const int t = (16 + qtp) * 64 + row;
    uint4* dst = (uint4*)(yb + (size_t)t * D_MODEL + h * HD + dseg);
    dst[0] = make_uint4(u[0], u[1], u[2], u[3]);
    dst[1] = make_uint4(u[4], u[5], u[6], u[7]);
}

// ---------------------------------------------------------------------------
// Kernel 3: output projection (bf16 MFMA, BK=64), fp32 out. grid=(8,16).
// ---------------------------------------------------------------------------
__global__ __launch_bounds__(256) void gemm_proj(
        const ushort_t* __restrict__ yb, const ushort_t* __restrict__ Wpb,
        float* __restrict__ out)
{
    const int row0 = blockIdx.y * 128;
    const int col0 = blockIdx.x * 128;

    __shared__ ushort_t As[128 * LDB];
    __shared__ ushort_t Bs[128 * LDB];

    const int tid = threadIdx.x;
    const int wave = tid >> 6, lane = tid & 63;
    const int wm = wave >> 1, wn = wave & 1;
    const int l15 = lane & 15, quad = lane >> 4;
    const int r_st = tid >> 1;
    const int c_st = (tid & 1) * 32;

    floatx4 acc[4][4];
    #pragma unroll
    for (int i = 0; i < 4; ++i)
        #pragma unroll
        for (int j = 0; j < 4; ++j)
            acc[i][j] = (floatx4){0.f, 0.f, 0.f, 0.f};

    for (int k0 = 0; k0 < D_MODEL; k0 += 64) {
        __syncthreads();
        cp16(As + r_st * LDB + c_st,      yb  + (size_t)(row0 + r_st) * D_MODEL + k0 + c_st);
        cp16(As + r_st * LDB + c_st + 16, yb  + (size_t)(row0 + r_st) * D_MODEL + k0 + c_st + 16);
        cp16(Bs + r_st * LDB + c_st,      Wpb + (size_t)(col0 + r_st) * D_MODEL + k0 + c_st);
        cp16(Bs + r_st * LDB + c_st + 16, Wpb + (size_t)(col0 + r_st) * D_MODEL + k0 + c_st + 16);
        __syncthreads();
        #pragma unroll
        for (int kh = 0; kh < 2; ++kh) {
            short8 a[4], b[4];
            #pragma unroll
            for (int i = 0; i < 4; ++i) {
                a[i] = *(const short8*)(As + (64 * wm + i * 16 + l15) * LDB + kh * 32 + quad * 8);
                b[i] = *(const short8*)(Bs + (64 * wn + i * 16 + l15) * LDB + kh * 32 + quad * 8);
            }
            #pragma unroll
            for (int i = 0; i < 4; ++i)
                #pragma unroll
                for (int j = 0; j < 4; ++j)
                    acc[i][j] = __builtin_amdgcn_mfma_f32_16x16x32_bf16(a[i], b[j], acc[i][j], 0, 0, 0);
        }
    }

    #pragma unroll
    for (int i = 0; i < 4; ++i)
        #pragma unroll
        for (int j = 0; j < 4; ++j) {
            const int t = row0 + 64 * wm + i * 16 + quad * 4;
            const int jj = col0 + 64 * wn + j * 16 + l15;
            #pragma unroll
            for (int r = 0; r < 4; ++r)
                out[(size_t)(t + r) * D_MODEL + jj] = acc[i][j][r];
        }
}

// ---------------------------------------------------------------------------
extern "C" void kernel_launch(void* const* d_in, const int* in_sizes, int n_in,
                              void* d_out, int out_size, void* d_ws, size_t ws_size,
                              hipStream_t stream) {
    (void)in_sizes; (void)n_in; (void)out_size; (void)ws_size;
    const float* x   = (const float*)d_in[0];
    const float* vi  = (const float*)d_in[1];
    const float* Wq  = (const float*)d_in[2];
    const float* Wk  = (const float*)d_in[3];
    const float* Wv  = (const float*)d_in[4];
    const float* Wp  = (const float*)d_in[5];
    const float* lam = (const float*)d_in[6];

    char* base = (char*)d_ws;                                  // 28 MiB used
    ushort_t* xb  = (ushort_t*)(base);                         // [ 0, 4) MiB (dead after gemm_qkv)
    ushort_t* wqb = (ushort_t*)(base + (size_t)4  * 1048576);  // [ 4, 6)  (dead after gemm_qkv)
    ushort_t* wkb = (ushort_t*)(base + (size_t)6  * 1048576);  // [ 6, 8)  (dead after gemm_qkv)
    ushort_t* wvb = (ushort_t*)(base + (size_t)8  * 1048576);  // [ 8,10)  (dead after gemm_qkv)
    ushort_t* wpb = (ushort_t*)(base + (size_t)10 * 1048576);  // [10,12)  (live until gemm_proj)
    ushort_t* qb  = (ushort_t*)(base + (size_t)12 * 1048576);  // [12,16)
    ushort_t* kb  = (ushort_t*)(base + (size_t)16 * 1048576);  // [16,20)
    ushort_t* vbt = (ushort_t*)(base + (size_t)20 * 1048576);  // [20,24)  [d][t]
    ushort_t* yb  = (ushort_t*)(base + (size_t)24 * 1048576);  // [24,28)
    // attn partials reuse [0, 8.2) MiB — dead xb/wqb/wkb/wvb space:
    float* Opart  = (float*)(base);                            // 512 * 4096 * 4B = 8 MiB
    float* Lpart  = (float*)(base + (size_t)8 * 1048576);      // 512 * 64 * 4B = 128 KiB
    float* out = (float*)d_out;

    to_bf16<<<dim3(786432 / 256), 256, 0, stream>>>(x, Wq, Wk, Wv, Wp, xb, wqb, wkb, wvb, wpb);
    gemm_qkv<<<dim3(8, 16, 3), 256, 0, stream>>>(xb, wqb, wkb, wvb, vi, lam, qb, kb, vbt);
    attn<<<dim3(48, 16), 256, 0, stream>>>(qb, kb, vbt, yb, Opart, Lpart);
    attn_combine<<<dim3(16, 16), 256, 0, stream>>>(Opart, Lpart, yb);
    gemm_proj<<<dim3(8, 16), 256, 0, stream>>>(yb, wpb, out);
}

// Round 4
// 157.495 us; speedup vs baseline: 1.2716x; 1.0836x over previous
//
#include <hip/hip_runtime.h>
#include <math.h>

#define T_SEQ 2048
#define D_MODEL 1024
#define NH 16
#define HD 64

typedef unsigned short ushort_t;
typedef unsigned int uint_t;
typedef short short8 __attribute__((ext_vector_type(8)));
typedef float floatx4 __attribute__((ext_vector_type(4)));

// ---- bf16 helpers (RNE) ----
__device__ __forceinline__ ushort_t f2bf(float f) {
    uint_t u = __float_as_uint(f);
    u += 0x7FFFu + ((u >> 16) & 1u);
    return (ushort_t)(u >> 16);
}
__device__ __forceinline__ uint_t pack2(float a, float b) {
    return (uint_t)f2bf(a) | ((uint_t)f2bf(b) << 16);
}
// copy 16 bf16 (32B) global/LDS (used by attn only)
__device__ __forceinline__ void cp16(ushort_t* dst, const ushort_t* src) {
    uint4 a = ((const uint4*)src)[0];
    uint4 b = ((const uint4*)src)[1];
    ((uint4*)dst)[0] = a;
    ((uint4*)dst)[1] = b;
}
// async global -> LDS, 16B per lane (wave-uniform LDS base + lane*16)
__device__ __forceinline__ void gload16(const ushort_t* g, ushort_t* l) {
    __builtin_amdgcn_global_load_lds(
        (const __attribute__((address_space(1))) void*)g,
        (__attribute__((address_space(3))) void*)l, 16, 0, 0);
}

#define LDK 72    // attn K/Q/P/V row stride (64 cols + 8 pad)

// ---------------------------------------------------------------------------
// Kernel 0: one-time fp32 -> bf16 convert of x, Wq, Wk, Wv, Wp.
// ---------------------------------------------------------------------------
__global__ __launch_bounds__(256) void to_bf16(
        const float* __restrict__ x,  const float* __restrict__ wq,
        const float* __restrict__ wk, const float* __restrict__ wv,
        const float* __restrict__ wp,
        ushort_t* __restrict__ xb,  ushort_t* __restrict__ wqb,
        ushort_t* __restrict__ wkb, ushort_t* __restrict__ wvb,
        ushort_t* __restrict__ wpb)
{
    size_t i = (size_t)blockIdx.x * 256 + threadIdx.x;
    const float* src; ushort_t* dst; size_t off;
    if (i < 262144)      { src = x;  dst = xb;  off = i; }
    else if (i < 393216) { src = wq; dst = wqb; off = i - 262144; }
    else if (i < 524288) { src = wk; dst = wkb; off = i - 393216; }
    else if (i < 655360) { src = wv; dst = wvb; off = i - 524288; }
    else                 { src = wp; dst = wpb; off = i - 655360; }
    float4 f0 = ((const float4*)src)[off * 2];
    float4 f1 = ((const float4*)src)[off * 2 + 1];
    uint4 u;
    u.x = pack2(f0.x, f0.y); u.y = pack2(f0.z, f0.w);
    u.z = pack2(f1.x, f1.y); u.w = pack2(f1.z, f1.w);
    ((uint4*)dst)[off] = u;
}

// ---------------------------------------------------------------------------
// Kernel 1: QKV GEMM (bf16 MFMA), BM=64 BN=128 BK=64, grid (8,32,3) = 768
// blocks = exactly 3/CU (balanced; was 384 = 1.5 rounds). Staging via
// global_load_lds width=16 into LINEAR LDS with XOR-swizzle:
//   writer: lane fetches logical slot (tid&7)^((tid>>3)&7) of its row
//   reader: phys slot = (kh*4+quad) ^ (row&7)          (same involution)
// -> rows r, r+8 alias = 2-way LDS conflict = free.
// FUSED RMSNorm+RoPE epilogue (z<2) / lambda-blend V transpose (z=2).
// Wave owns 32 rows (wm) x 64 cols (wn) = one head's columns.
// ---------------------------------------------------------------------------
__global__ __launch_bounds__(256) void gemm_qkv(
        const ushort_t* __restrict__ xb,
        const ushort_t* __restrict__ Wqb, const ushort_t* __restrict__ Wkb,
        const ushort_t* __restrict__ Wvb,
        const float* __restrict__ vi, const float* __restrict__ lam,
        ushort_t* __restrict__ qb, ushort_t* __restrict__ kb,
        ushort_t* __restrict__ vbt)
{
    const int z = blockIdx.z;
    const ushort_t* __restrict__ W = (z == 0) ? Wqb : (z == 1) ? Wkb : Wvb;
    const int row0 = blockIdx.y * 64;
    const int col0 = blockIdx.x * 128;

    __shared__ ushort_t As[64 * 64];     // linear, swizzled content
    __shared__ ushort_t Bs[128 * 64];

    const int tid = threadIdx.x;
    const int wave = tid >> 6, lane = tid & 63;
    const int wm = wave >> 1, wn = wave & 1;
    const int l15 = lane & 15, quad = lane >> 4;
    const int srow  = tid >> 3;                     // staging row 0..31
    const int sslot = (tid & 7) ^ (srow & 7);       // pre-swizzled 16B slot

    floatx4 acc[2][4];
    #pragma unroll
    for (int i = 0; i < 2; ++i)
        #pragma unroll
        for (int j = 0; j < 4; ++j)
            acc[i][j] = (floatx4){0.f, 0.f, 0.f, 0.f};

    for (int k0 = 0; k0 < D_MODEL; k0 += 64) {
        __syncthreads();
        #pragma unroll
        for (int c = 0; c < 2; ++c)
            gload16(xb + (size_t)(row0 + c * 32 + srow) * D_MODEL + k0 + sslot * 8,
                    As + c * 2048 + tid * 8);
        #pragma unroll
        for (int c = 0; c < 4; ++c)
            gload16(W + (size_t)(col0 + c * 32 + srow) * D_MODEL + k0 + sslot * 8,
                    Bs + c * 2048 + tid * 8);
        __syncthreads();   // drains vmcnt(0) (global_load_lds) before use
        #pragma unroll
        for (int kh = 0; kh < 2; ++kh) {
            const int slot = ((kh * 4 + quad) ^ (l15 & 7)) << 3;  // ushort offs
            short8 a[2], b[4];
            #pragma unroll
            for (int i = 0; i < 2; ++i)
                a[i] = *(const short8*)(As + (32 * wm + i * 16 + l15) * 64 + slot);
            #pragma unroll
            for (int j = 0; j < 4; ++j)
                b[j] = *(const short8*)(Bs + (64 * wn + j * 16 + l15) * 64 + slot);
            #pragma unroll
            for (int i = 0; i < 2; ++i)
                #pragma unroll
                for (int j = 0; j < 4; ++j)
                    acc[i][j] = __builtin_amdgcn_mfma_f32_16x16x32_bf16(a[i], b[j], acc[i][j], 0, 0, 0);
        }
    }

    if (z < 2) {
        ushort_t* __restrict__ o = (z == 0) ? qb : kb;
        const float oscale = (z == 0) ? 0.125f : 1.0f;   // fold 1/sqrt(hd) into q
        const int hbase = col0 + 64 * wn;
        const float eps = 1.1920929e-7f;
        const float fr = exp2f(-10.0f * (float)l15 / 15.0f);  // rotating-pair freq
        #pragma unroll
        for (int i = 0; i < 2; ++i)
            #pragma unroll
            for (int r = 0; r < 4; ++r) {
                const int t = row0 + 32 * wm + i * 16 + quad * 4 + r;
                float v0 = acc[i][0][r], v1 = acc[i][1][r];
                float v2 = acc[i][2][r], v3 = acc[i][3][r];
                float ss = v0 * v0 + v1 * v1 + v2 * v2 + v3 * v3;
                ss += __shfl_xor(ss, 1);
                ss += __shfl_xor(ss, 2);
                ss += __shfl_xor(ss, 4);
                ss += __shfl_xor(ss, 8);
                const float sc = rsqrtf(ss * (1.0f / 64.0f) + eps);
                v0 *= sc; v1 *= sc; v2 *= sc; v3 *= sc;
                const float th = (float)t * fr;
                const float cs = cosf(th), sn = sinf(th);
                const float y0 = v0 * cs + v2 * sn;   // shown-source rotary sign
                const float y2 = v2 * cs - v0 * sn;
                const size_t rb = (size_t)t * D_MODEL + hbase;
                o[rb +  0 + l15] = f2bf(y0 * oscale);
                o[rb + 16 + l15] = f2bf(v1 * oscale);
                o[rb + 32 + l15] = f2bf(y2 * oscale);
                o[rb + 48 + l15] = f2bf(v3 * oscale);
            }
    } else {
        const float l0 = lam[0], l1 = lam[1];
        #pragma unroll
        for (int i = 0; i < 2; ++i)
            #pragma unroll
            for (int j = 0; j < 4; ++j) {
                const int tb = row0 + 32 * wm + i * 16 + quad * 4;
                const int jj = col0 + 64 * wn + j * 16 + l15;
                float b0 = l0 * acc[i][j][0] + l1 * vi[(size_t)(tb + 0) * D_MODEL + jj];
                float b1 = l0 * acc[i][j][1] + l1 * vi[(size_t)(tb + 1) * D_MODEL + jj];
                float b2 = l0 * acc[i][j][2] + l1 * vi[(size_t)(tb + 2) * D_MODEL + jj];
                float b3 = l0 * acc[i][j][3] + l1 * vi[(size_t)(tb + 3) * D_MODEL + jj];
                uint2 u;
                u.x = pack2(b0, b1);
                u.y = pack2(b2, b3);
                *(uint2*)(vbt + (size_t)jj * T_SEQ + tb) = u;   // [d][t]
            }
    }
}

// ---------------------------------------------------------------------------
// Kernel 2: MFMA flash attention, KV-split, FIXED-MAX softmax (unchanged).
// Scores provably bounded |s|<=8 (RMSNorm + folded 1/8) => constant max.
// LDS 27.6 KB -> 5 blocks/CU. Work split per head (big-first):
//   x in [ 0,16): qt = 31-x,  KV [0, mid)     -> fp32 partial chunk 0
//   x in [16,32): qt = 47-x,  KV [mid, qt+1)  -> fp32 partial chunk 1 (diag)
//   x in [32,48): qt = 47-x,  KV [0, qt+1)    -> direct bf16 write
// ---------------------------------------------------------------------------
__global__ __launch_bounds__(256) void attn(
        const ushort_t* __restrict__ qb, const ushort_t* __restrict__ kb,
        const ushort_t* __restrict__ vbt, ushort_t* __restrict__ yb,
        float* __restrict__ Opart, float* __restrict__ Lpart)
{
    const int h = blockIdx.y;
    const int x = blockIdx.x;
    int qt, ct_begin, ct_end, pidx;
    if (x < 16) {                       // chunk 0 of qt>=16 (dense, no mask hit)
        qt = 31 - x;
        const int mid = (qt + 2) >> 1;
        ct_begin = 0; ct_end = mid;
        pidx = ((h * 16 + (qt - 16)) << 1);
    } else if (x < 32) {                // chunk 1 of qt>=16 (contains diagonal)
        qt = 47 - x;
        const int mid = (qt + 2) >> 1;
        ct_begin = mid; ct_end = qt + 1;
        pidx = ((h * 16 + (qt - 16)) << 1) + 1;
    } else {                            // direct, qt in [0,15]
        qt = 47 - x;
        ct_begin = 0; ct_end = qt + 1;
        pidx = -1;
    }
    const int t0 = qt * 64;

    __shared__ ushort_t Ks[64 * LDK];    // [s_local][d]
    __shared__ ushort_t Vs[64 * LDK];    // [d][s_local]
    __shared__ ushort_t QPs[64 * LDK];   // Q tile, then reused for P

    const int tid = threadIdx.x;
    const int wave = tid >> 6, lane = tid & 63;
    const int l15 = lane & 15, quad = lane >> 4;
    const int r4 = tid >> 2, c4 = (tid & 3) * 16;   // staging: 1 cp16/thread

    // stage Q (64x64)
    cp16(QPs + r4 * LDK + c4, qb + (size_t)(t0 + r4) * D_MODEL + h * HD + c4);
    __syncthreads();
    short8 qf[2];
    qf[0] = *(const short8*)(QPs + (16 * wave + l15) * LDK + 0  + quad * 8);
    qf[1] = *(const short8*)(QPs + (16 * wave + l15) * LDK + 32 + quad * 8);

    float l_acc[4];
    floatx4 O[4];
    #pragma unroll
    for (int r = 0; r < 4; ++r) l_acc[r] = 0.0f;
    #pragma unroll
    for (int d = 0; d < 4; ++d) O[d] = (floatx4){0.f, 0.f, 0.f, 0.f};

    for (int kt = ct_begin; kt < ct_end; ++kt) {
        const int s0 = kt * 64;
        __syncthreads();
        // stage K: 64 s-rows x 64 d-cols; V: 64 d-rows x 64 s-cols
        cp16(Ks + r4 * LDK + c4, kb  + (size_t)(s0 + r4) * D_MODEL + h * HD + c4);
        cp16(Vs + r4 * LDK + c4, vbt + (size_t)(h * HD + r4) * T_SEQ + s0 + c4);
        __syncthreads();

        floatx4 sa[4];
        #pragma unroll
        for (int ct = 0; ct < 4; ++ct) {
            short8 b0 = *(const short8*)(Ks + (ct * 16 + l15) * LDK + 0  + quad * 8);
            short8 b1 = *(const short8*)(Ks + (ct * 16 + l15) * LDK + 32 + quad * 8);
            floatx4 t4 = (floatx4){0.f, 0.f, 0.f, 0.f};
            t4 = __builtin_amdgcn_mfma_f32_16x16x32_bf16(qf[0], b0, t4, 0, 0, 0);
            t4 = __builtin_amdgcn_mfma_f32_16x16x32_bf16(qf[1], b1, t4, 0, 0, 0);
            sa[ct] = t4;
        }
        if (kt == qt) {   // causal mask on the diagonal tile
            #pragma unroll
            for (int ct = 0; ct < 4; ++ct)
                #pragma unroll
                for (int r = 0; r < 4; ++r) {
                    int trow = 16 * wave + quad * 4 + r;
                    int scol = ct * 16 + l15;
                    if (scol > trow) sa[ct][r] = -1e30f;
                }
        }
        // fixed-max softmax: p = exp(s - 8), per-lane l accumulation only
        float p[4][4];
        #pragma unroll
        for (int ct = 0; ct < 4; ++ct)
            #pragma unroll
            for (int r = 0; r < 4; ++r) {
                p[ct][r] = __expf(sa[ct][r] - 8.0f);
                l_acc[r] += p[ct][r];
            }

        // P -> LDS (wave-private 16-row stripe; no barrier needed)
        #pragma unroll
        for (int ct = 0; ct < 4; ++ct)
            #pragma unroll
            for (int r = 0; r < 4; ++r)
                QPs[(16 * wave + quad * 4 + r) * LDK + ct * 16 + l15] = f2bf(p[ct][r]);

        short8 pa0 = *(const short8*)(QPs + (16 * wave + l15) * LDK + 0  + quad * 8);
        short8 pa1 = *(const short8*)(QPs + (16 * wave + l15) * LDK + 32 + quad * 8);
        #pragma unroll
        for (int dt = 0; dt < 4; ++dt) {
            short8 vb0 = *(const short8*)(Vs + (dt * 16 + l15) * LDK + 0  + quad * 8);
            short8 vb1 = *(const short8*)(Vs + (dt * 16 + l15) * LDK + 32 + quad * 8);
            O[dt] = __builtin_amdgcn_mfma_f32_16x16x32_bf16(pa0, vb0, O[dt], 0, 0, 0);
            O[dt] = __builtin_amdgcn_mfma_f32_16x16x32_bf16(pa1, vb1, O[dt], 0, 0, 0);
        }
    }

    // one-time row-sum reduce across the 16 col-lanes
    float l_run[4];
    #pragma unroll
    for (int r = 0; r < 4; ++r) {
        float s = l_acc[r];
        s += __shfl_xor(s, 1);
        s += __shfl_xor(s, 2);
        s += __shfl_xor(s, 4);
        s += __shfl_xor(s, 8);
        l_run[r] = s;
    }

    if (pidx < 0) {
        // direct: normalize and write bf16
        #pragma unroll
        for (int r = 0; r < 4; ++r) {
            const float inv_l = 1.0f / l_run[r];
            const int t = t0 + 16 * wave + quad * 4 + r;
            #pragma unroll
            for (int dt = 0; dt < 4; ++dt)
                yb[(size_t)t * D_MODEL + h * HD + dt * 16 + l15] = f2bf(O[dt][r] * inv_l);
        }
    } else {
        // partial: unnormalized fp32 O + per-row l (fixed max => no m needed)
        float* __restrict__ Op = Opart + (size_t)pidx * 4096;
        #pragma unroll
        for (int r = 0; r < 4; ++r) {
            const int row = 16 * wave + quad * 4 + r;
            #pragma unroll
            for (int dt = 0; dt < 4; ++dt)
                Op[row * 64 + dt * 16 + l15] = O[dt][r];
            if (l15 == 0) Lpart[(size_t)pidx * 64 + row] = l_run[r];
        }
    }
}

// ---------------------------------------------------------------------------
// Kernel 2b: combine the two KV-chunk partials for qt in [16,32).
// Fixed max on both chunks => combined = (O0 + O1) / (l0 + l1).
// ---------------------------------------------------------------------------
__global__ __launch_bounds__(256) void attn_combine(
        const float* __restrict__ Opart, const float* __restrict__ Lpart,
        ushort_t* __restrict__ yb)
{
    const int qtp = blockIdx.x;          // qt = 16 + qtp
    const int h   = blockIdx.y;
    const int tid = threadIdx.x;
    const int row  = tid >> 2;           // 0..63
    const int dseg = (tid & 3) * 16;     // 0/16/32/48
    const int p0 = (h * 16 + qtp) * 2;

    const float l0 = Lpart[(size_t)p0 * 64 + row];
    const float l1 = Lpart[((size_t)p0 + 1) * 64 + row];
    const float inv = 1.0f / (l0 + l1);

    const float* O0 = Opart + (size_t)p0 * 4096 + row * 64 + dseg;
    const float* O1 = O0 + 4096;

    uint_t u[8];
    #pragma unroll
    for (int g = 0; g < 4; ++g) {
        float4 a = ((const float4*)O0)[g];
        float4 b = ((const float4*)O1)[g];
        u[g * 2 + 0] = pack2((a.x + b.x) * inv, (a.y + b.y) * inv);
        u[g * 2 + 1] = pack2((a.z + b.z) * inv, (a.w + b.w) * inv);
    }
    const int t = (16 + qtp) * 64 + row;
    uint4* dst = (uint4*)(yb + (size_t)t * D_MODEL + h * HD + dseg);
    dst[0] = make_uint4(u[0], u[1], u[2], u[3]);
    dst[1] = make_uint4(u[4], u[5], u[6], u[7]);
}

// ---------------------------------------------------------------------------
// Kernel 3: output projection, BM=64 BN=128 BK=64, grid (8,32) = 256 blocks
// = exactly 1/CU (was 128 blocks = half the machine idle). Same
// global_load_lds + XOR-swizzle staging as gemm_qkv. fp32 out.
// ---------------------------------------------------------------------------
__global__ __launch_bounds__(256) void gemm_proj(
        const ushort_t* __restrict__ yb, const ushort_t* __restrict__ Wpb,
        float* __restrict__ out)
{
    const int row0 = blockIdx.y * 64;
    const int col0 = blockIdx.x * 128;

    __shared__ ushort_t As[64 * 64];
    __shared__ ushort_t Bs[128 * 64];

    const int tid = threadIdx.x;
    const int wave = tid >> 6, lane = tid & 63;
    const int wm = wave >> 1, wn = wave & 1;
    const int l15 = lane & 15, quad = lane >> 4;
    const int srow  = tid >> 3;
    const int sslot = (tid & 7) ^ (srow & 7);

    floatx4 acc[2][4];
    #pragma unroll
    for (int i = 0; i < 2; ++i)
        #pragma unroll
        for (int j = 0; j < 4; ++j)
            acc[i][j] = (floatx4){0.f, 0.f, 0.f, 0.f};

    for (int k0 = 0; k0 < D_MODEL; k0 += 64) {
        __syncthreads();
        #pragma unroll
        for (int c = 0; c < 2; ++c)
            gload16(yb + (size_t)(row0 + c * 32 + srow) * D_MODEL + k0 + sslot * 8,
                    As + c * 2048 + tid * 8);
        #pragma unroll
        for (int c = 0; c < 4; ++c)
            gload16(Wpb + (size_t)(col0 + c * 32 + srow) * D_MODEL + k0 + sslot * 8,
                    Bs + c * 2048 + tid * 8);
        __syncthreads();
        #pragma unroll
        for (int kh = 0; kh < 2; ++kh) {
            const int slot = ((kh * 4 + quad) ^ (l15 & 7)) << 3;
            short8 a[2], b[4];
            #pragma unroll
            for (int i = 0; i < 2; ++i)
                a[i] = *(const short8*)(As + (32 * wm + i * 16 + l15) * 64 + slot);
            #pragma unroll
            for (int j = 0; j < 4; ++j)
                b[j] = *(const short8*)(Bs + (64 * wn + j * 16 + l15) * 64 + slot);
            #pragma unroll
            for (int i = 0; i < 2; ++i)
                #pragma unroll
                for (int j = 0; j < 4; ++j)
                    acc[i][j] = __builtin_amdgcn_mfma_f32_16x16x32_bf16(a[i], b[j], acc[i][j], 0, 0, 0);
        }
    }

    #pragma unroll
    for (int i = 0; i < 2; ++i)
        #pragma unroll
        for (int j = 0; j < 4; ++j) {
            const int t = row0 + 32 * wm + i * 16 + quad * 4;
            const int jj = col0 + 64 * wn + j * 16 + l15;
            #pragma unroll
            for (int r = 0; r < 4; ++r)
                out[(size_t)(t + r) * D_MODEL + jj] = acc[i][j][r];
        }
}

// ---------------------------------------------------------------------------
extern "C" void kernel_launch(void* const* d_in, const int* in_sizes, int n_in,
                              void* d_out, int out_size, void* d_ws, size_t ws_size,
                              hipStream_t stream) {
    (void)in_sizes; (void)n_in; (void)out_size; (void)ws_size;
    const float* x   = (const float*)d_in[0];
    const float* vi  = (const float*)d_in[1];
    const float* Wq  = (const float*)d_in[2];
    const float* Wk  = (const float*)d_in[3];
    const float* Wv  = (const float*)d_in[4];
    const float* Wp  = (const float*)d_in[5];
    const float* lam = (const float*)d_in[6];

    char* base = (char*)d_ws;                                  // 28 MiB used
    ushort_t* xb  = (ushort_t*)(base);                         // [ 0, 4) MiB (dead after gemm_qkv)
    ushort_t* wqb = (ushort_t*)(base + (size_t)4  * 1048576);  // [ 4, 6)  (dead after gemm_qkv)
    ushort_t* wkb = (ushort_t*)(base + (size_t)6  * 1048576);  // [ 6, 8)  (dead after gemm_qkv)
    ushort_t* wvb = (ushort_t*)(base + (size_t)8  * 1048576);  // [ 8,10)  (dead after gemm_qkv)
    ushort_t* wpb = (ushort_t*)(base + (size_t)10 * 1048576);  // [10,12)  (live until gemm_proj)
    ushort_t* qb  = (ushort_t*)(base + (size_t)12 * 1048576);  // [12,16)
    ushort_t* kb  = (ushort_t*)(base + (size_t)16 * 1048576);  // [16,20)
    ushort_t* vbt = (ushort_t*)(base + (size_t)20 * 1048576);  // [20,24)  [d][t]
    ushort_t* yb  = (ushort_t*)(base + (size_t)24 * 1048576);  // [24,28)
    // attn partials reuse [0, 8.2) MiB — dead xb/wqb/wkb/wvb space:
    float* Opart  = (float*)(base);                            // 512 * 4096 * 4B = 8 MiB
    float* Lpart  = (float*)(base + (size_t)8 * 1048576);      // 512 * 64 * 4B = 128 KiB
    float* out = (float*)d_out;

    to_bf16<<<dim3(786432 / 256), 256, 0, stream>>>(x, Wq, Wk, Wv, Wp, xb, wqb, wkb, wvb, wpb);
    gemm_qkv<<<dim3(8, 32, 3), 256, 0, stream>>>(xb, wqb, wkb, wvb, vi, lam, qb, kb, vbt);
    attn<<<dim3(48, 16), 256, 0, stream>>>(qb, kb, vbt, yb, Opart, Lpart);
    attn_combine<<<dim3(16, 16), 256, 0, stream>>>(Opart, Lpart, yb);
    gemm_proj<<<dim3(8, 32), 256, 0, stream>>>(yb, wpb, out);
}

// Round 6
// 149.678 us; speedup vs baseline: 1.3380x; 1.0522x over previous
//
#include <hip/hip_runtime.h>
#include <math.h>

#define T_SEQ 2048
#define D_MODEL 1024
#define NH 16
#define HD 64

typedef unsigned short ushort_t;
typedef unsigned int uint_t;
typedef short short8 __attribute__((ext_vector_type(8)));
typedef float floatx4 __attribute__((ext_vector_type(4)));

// ---- bf16 helpers (RNE) ----
__device__ __forceinline__ ushort_t f2bf(float f) {
    uint_t u = __float_as_uint(f);
    u += 0x7FFFu + ((u >> 16) & 1u);
    return (ushort_t)(u >> 16);
}
__device__ __forceinline__ uint_t pack2(float a, float b) {
    return (uint_t)f2bf(a) | ((uint_t)f2bf(b) << 16);
}
// copy 16 bf16 (32B) global/LDS (attn Q stage only)
__device__ __forceinline__ void cp16(ushort_t* dst, const ushort_t* src) {
    uint4 a = ((const uint4*)src)[0];
    uint4 b = ((const uint4*)src)[1];
    ((uint4*)dst)[0] = a;
    ((uint4*)dst)[1] = b;
}
// async global -> LDS, 16B per lane (wave-uniform LDS base + lane*16)
__device__ __forceinline__ void gload16(const ushort_t* g, ushort_t* l) {
    __builtin_amdgcn_global_load_lds(
        (const __attribute__((address_space(1))) void*)g,
        (__attribute__((address_space(3))) void*)l, 16, 0, 0);
}

#define LDK 72    // attn Q/P row stride (64 cols + 8 pad)

// ---------------------------------------------------------------------------
// Kernel 0: one-time fp32 -> bf16 convert of x, Wq, Wk, Wv, Wp.
// ---------------------------------------------------------------------------
__global__ __launch_bounds__(256) void to_bf16(
        const float* __restrict__ x,  const float* __restrict__ wq,
        const float* __restrict__ wk, const float* __restrict__ wv,
        const float* __restrict__ wp,
        ushort_t* __restrict__ xb,  ushort_t* __restrict__ wqb,
        ushort_t* __restrict__ wkb, ushort_t* __restrict__ wvb,
        ushort_t* __restrict__ wpb)
{
    size_t i = (size_t)blockIdx.x * 256 + threadIdx.x;
    const float* src; ushort_t* dst; size_t off;
    if (i < 262144)      { src = x;  dst = xb;  off = i; }
    else if (i < 393216) { src = wq; dst = wqb; off = i - 262144; }
    else if (i < 524288) { src = wk; dst = wkb; off = i - 393216; }
    else if (i < 655360) { src = wv; dst = wvb; off = i - 524288; }
    else                 { src = wp; dst = wpb; off = i - 655360; }
    float4 f0 = ((const float4*)src)[off * 2];
    float4 f1 = ((const float4*)src)[off * 2 + 1];
    uint4 u;
    u.x = pack2(f0.x, f0.y); u.y = pack2(f0.z, f0.w);
    u.z = pack2(f1.x, f1.y); u.w = pack2(f1.z, f1.w);
    ((uint4*)dst)[off] = u;
}

// ---------------------------------------------------------------------------
// Kernel 1: QKV GEMM (bf16 MFMA), BM=64 BN=128 BK=64, grid (8,32,3) = 768
// blocks = 3/CU. 2-PHASE double-buffered staging: global_load_lds width=16,
// issue next tile BEFORE computing current, counted s_waitcnt vmcnt(6) + raw
// s_barrier (never drain to 0 mid-loop). XOR-swizzle: writer fetches logical
// slot (tid&7)^(row&7); reader uses phys slot (kh*4+quad)^(row&7).
// FUSED RMSNorm+RoPE epilogue (z<2) / lambda-blend V transpose (z=2).
// ---------------------------------------------------------------------------
__global__ __launch_bounds__(256) void gemm_qkv(
        const ushort_t* __restrict__ xb,
        const ushort_t* __restrict__ Wqb, const ushort_t* __restrict__ Wkb,
        const ushort_t* __restrict__ Wvb,
        const float* __restrict__ vi, const float* __restrict__ lam,
        ushort_t* __restrict__ qb, ushort_t* __restrict__ kb,
        ushort_t* __restrict__ vbt)
{
    const int z = blockIdx.z;
    const ushort_t* __restrict__ W = (z == 0) ? Wqb : (z == 1) ? Wkb : Wvb;
    const int row0 = blockIdx.y * 64;
    const int col0 = blockIdx.x * 128;

    __shared__ ushort_t As[2 * 64 * 64];     // 16 KB (2 buffers)
    __shared__ ushort_t Bs[2 * 128 * 64];    // 32 KB

    const int tid = threadIdx.x;
    const int wave = tid >> 6, lane = tid & 63;
    const int wm = wave >> 1, wn = wave & 1;
    const int l15 = lane & 15, quad = lane >> 4;
    const int srow  = tid >> 3;                     // staging row 0..31
    const int sslot = (tid & 7) ^ (srow & 7);       // pre-swizzled 16B slot

    floatx4 acc[2][4];
    #pragma unroll
    for (int i = 0; i < 2; ++i)
        #pragma unroll
        for (int j = 0; j < 4; ++j)
            acc[i][j] = (floatx4){0.f, 0.f, 0.f, 0.f};

    // stage tile at k-offset k0 into buffer p (6 gloads/wave)
    auto stageAB = [&](int k0, int p) {
        ushort_t* Ap = As + p * 4096;
        ushort_t* Bp = Bs + p * 8192;
        #pragma unroll
        for (int c = 0; c < 2; ++c)
            gload16(xb + (size_t)(row0 + c * 32 + srow) * D_MODEL + k0 + sslot * 8,
                    Ap + c * 2048 + tid * 8);
        #pragma unroll
        for (int c = 0; c < 4; ++c)
            gload16(W + (size_t)(col0 + c * 32 + srow) * D_MODEL + k0 + sslot * 8,
                    Bp + c * 2048 + tid * 8);
    };

    stageAB(0, 0);
    int cur = 0;
    for (int knext = 64; knext <= D_MODEL; knext += 64) {
        const bool haveNext = (knext < D_MODEL);
        if (haveNext) {
            stageAB(knext, cur ^ 1);
            asm volatile("s_waitcnt vmcnt(6)" ::: "memory");
        } else {
            asm volatile("s_waitcnt vmcnt(0)" ::: "memory");
        }
        __builtin_amdgcn_s_barrier();
        const ushort_t* Ac = As + cur * 4096;
        const ushort_t* Bc = Bs + cur * 8192;
        #pragma unroll
        for (int kh = 0; kh < 2; ++kh) {
            const int slot = ((kh * 4 + quad) ^ (l15 & 7)) << 3;  // ushort offs
            short8 a[2], b[4];
            #pragma unroll
            for (int i = 0; i < 2; ++i)
                a[i] = *(const short8*)(Ac + (32 * wm + i * 16 + l15) * 64 + slot);
            #pragma unroll
            for (int j = 0; j < 4; ++j)
                b[j] = *(const short8*)(Bc + (64 * wn + j * 16 + l15) * 64 + slot);
            #pragma unroll
            for (int i = 0; i < 2; ++i)
                #pragma unroll
                for (int j = 0; j < 4; ++j)
                    acc[i][j] = __builtin_amdgcn_mfma_f32_16x16x32_bf16(a[i], b[j], acc[i][j], 0, 0, 0);
        }
        asm volatile("" ::: "memory");
        __builtin_amdgcn_s_barrier();   // protect buf before next overwrite
        cur ^= 1;
    }

    if (z < 2) {
        ushort_t* __restrict__ o = (z == 0) ? qb : kb;
        const float oscale = (z == 0) ? 0.125f : 1.0f;   // fold 1/sqrt(hd) into q
        const int hbase = col0 + 64 * wn;
        const float eps = 1.1920929e-7f;
        const float fr = exp2f(-10.0f * (float)l15 / 15.0f);  // rotating-pair freq
        #pragma unroll
        for (int i = 0; i < 2; ++i)
            #pragma unroll
            for (int r = 0; r < 4; ++r) {
                const int t = row0 + 32 * wm + i * 16 + quad * 4 + r;
                float v0 = acc[i][0][r], v1 = acc[i][1][r];
                float v2 = acc[i][2][r], v3 = acc[i][3][r];
                float ss = v0 * v0 + v1 * v1 + v2 * v2 + v3 * v3;
                ss += __shfl_xor(ss, 1);
                ss += __shfl_xor(ss, 2);
                ss += __shfl_xor(ss, 4);
                ss += __shfl_xor(ss, 8);
                const float sc = rsqrtf(ss * (1.0f / 64.0f) + eps);
                v0 *= sc; v1 *= sc; v2 *= sc; v3 *= sc;
                const float th = (float)t * fr;
                const float cs = cosf(th), sn = sinf(th);
                const float y0 = v0 * cs + v2 * sn;   // shown-source rotary sign
                const float y2 = v2 * cs - v0 * sn;
                const size_t rb = (size_t)t * D_MODEL + hbase;
                o[rb +  0 + l15] = f2bf(y0 * oscale);
                o[rb + 16 + l15] = f2bf(v1 * oscale);
                o[rb + 32 + l15] = f2bf(y2 * oscale);
                o[rb + 48 + l15] = f2bf(v3 * oscale);
            }
    } else {
        const float l0 = lam[0], l1 = lam[1];
        #pragma unroll
        for (int i = 0; i < 2; ++i)
            #pragma unroll
            for (int j = 0; j < 4; ++j) {
                const int tb = row0 + 32 * wm + i * 16 + quad * 4;
                const int jj = col0 + 64 * wn + j * 16 + l15;
                float b0 = l0 * acc[i][j][0] + l1 * vi[(size_t)(tb + 0) * D_MODEL + jj];
                float b1 = l0 * acc[i][j][1] + l1 * vi[(size_t)(tb + 1) * D_MODEL + jj];
                float b2 = l0 * acc[i][j][2] + l1 * vi[(size_t)(tb + 2) * D_MODEL + jj];
                float b3 = l0 * acc[i][j][3] + l1 * vi[(size_t)(tb + 3) * D_MODEL + jj];
                uint2 u;
                u.x = pack2(b0, b1);
                u.y = pack2(b2, b3);
                *(uint2*)(vbt + (size_t)jj * T_SEQ + tb) = u;   // [d][t]
            }
    }
}

// ---------------------------------------------------------------------------
// Kernel 2: MFMA flash attention, KV-split, FIXED-MAX softmax, 2-PHASE
// double-buffered K/V staging via global_load_lds (linear [64][64] + XOR
// swizzle, counted vmcnt(4) + raw s_barrier). |s|<=8 provable bound =>
// constant softmax max. LDS 41.2 KB -> 3 blocks/CU (all 768 blocks resident).
// Work split per head (big-first):
//   x in [ 0,16): qt = 31-x,  KV [0, mid)     -> fp32 partial chunk 0
//   x in [16,32): qt = 47-x,  KV [mid, qt+1)  -> fp32 partial chunk 1 (diag)
//   x in [32,48): qt = 47-x,  KV [0, qt+1)    -> direct bf16 write
// ---------------------------------------------------------------------------
__global__ __launch_bounds__(256) void attn(
        const ushort_t* __restrict__ qb, const ushort_t* __restrict__ kb,
        const ushort_t* __restrict__ vbt, ushort_t* __restrict__ yb,
        float* __restrict__ Opart, float* __restrict__ Lpart)
{
    const int h = blockIdx.y;
    const int x = blockIdx.x;
    int qt, ct_begin, ct_end, pidx;
    if (x < 16) {                       // chunk 0 of qt>=16 (dense, no mask hit)
        qt = 31 - x;
        const int mid = (qt + 2) >> 1;
        ct_begin = 0; ct_end = mid;
        pidx = ((h * 16 + (qt - 16)) << 1);
    } else if (x < 32) {                // chunk 1 of qt>=16 (contains diagonal)
        qt = 47 - x;
        const int mid = (qt + 2) >> 1;
        ct_begin = mid; ct_end = qt + 1;
        pidx = ((h * 16 + (qt - 16)) << 1) + 1;
    } else {                            // direct, qt in [0,15]
        qt = 47 - x;
        ct_begin = 0; ct_end = qt + 1;
        pidx = -1;
    }
    const int t0 = qt * 64;

    __shared__ ushort_t Ks[2 * 64 * 64];   // [s_local][d] linear, swizzled
    __shared__ ushort_t Vs[2 * 64 * 64];   // [d][s_local] linear, swizzled
    __shared__ ushort_t QPs[64 * LDK];     // Q tile, then reused for P

    const int tid = threadIdx.x;
    const int wave = tid >> 6, lane = tid & 63;
    const int l15 = lane & 15, quad = lane >> 4;
    const int r4 = tid >> 2, c4 = (tid & 3) * 16;
    const int srow  = tid >> 3;                   // staging row 0..31
    const int sslot = (tid & 7) ^ (srow & 7);     // pre-swizzled 16B slot
    const int bx = l15 & 7;

    // stage Q (64x64) once
    cp16(QPs + r4 * LDK + c4, qb + (size_t)(t0 + r4) * D_MODEL + h * HD + c4);
    __syncthreads();
    short8 qf[2];
    qf[0] = *(const short8*)(QPs + (16 * wave + l15) * LDK + 0  + quad * 8);
    qf[1] = *(const short8*)(QPs + (16 * wave + l15) * LDK + 32 + quad * 8);

    auto stageKV = [&](int kt, int p) {
        const int s0 = kt * 64;
        ushort_t* Kp = Ks + p * 4096;
        ushort_t* Vp = Vs + p * 4096;
        gload16(kb  + (size_t)(s0 + srow)      * D_MODEL + h * HD + sslot * 8, Kp + tid * 8);
        gload16(kb  + (size_t)(s0 + 32 + srow) * D_MODEL + h * HD + sslot * 8, Kp + 2048 + tid * 8);
        gload16(vbt + (size_t)(h * HD + srow)      * T_SEQ + s0 + sslot * 8,   Vp + tid * 8);
        gload16(vbt + (size_t)(h * HD + 32 + srow) * T_SEQ + s0 + sslot * 8,   Vp + 2048 + tid * 8);
    };

    float l_acc[4];
    floatx4 O[4];
    #pragma unroll
    for (int r = 0; r < 4; ++r) l_acc[r] = 0.0f;
    #pragma unroll
    for (int d = 0; d < 4; ++d) O[d] = (floatx4){0.f, 0.f, 0.f, 0.f};

    stageKV(ct_begin, 0);
    int cur = 0;
    for (int kt = ct_begin; kt < ct_end; ++kt) {
        const bool haveNext = (kt + 1 < ct_end);
        if (haveNext) {
            stageKV(kt + 1, cur ^ 1);
            asm volatile("s_waitcnt vmcnt(4)" ::: "memory");
        } else {
            asm volatile("s_waitcnt vmcnt(0)" ::: "memory");
        }
        __builtin_amdgcn_s_barrier();

        const ushort_t* Kc = Ks + cur * 4096;
        const ushort_t* Vc = Vs + cur * 4096;

        floatx4 sa[4];
        #pragma unroll
        for (int ct = 0; ct < 4; ++ct) {
            const ushort_t* krow = Kc + (ct * 16 + l15) * 64;
            short8 b0 = *(const short8*)(krow + ((quad ^ bx) << 3));
            short8 b1 = *(const short8*)(krow + (((quad + 4) ^ bx) << 3));
            floatx4 t4 = (floatx4){0.f, 0.f, 0.f, 0.f};
            t4 = __builtin_amdgcn_mfma_f32_16x16x32_bf16(qf[0], b0, t4, 0, 0, 0);
            t4 = __builtin_amdgcn_mfma_f32_16x16x32_bf16(qf[1], b1, t4, 0, 0, 0);
            sa[ct] = t4;
        }
        if (kt == qt) {   // causal mask on the diagonal tile
            #pragma unroll
            for (int ct = 0; ct < 4; ++ct)
                #pragma unroll
                for (int r = 0; r < 4; ++r) {
                    int trow = 16 * wave + quad * 4 + r;
                    int scol = ct * 16 + l15;
                    if (scol > trow) sa[ct][r] = -1e30f;
                }
        }
        // fixed-max softmax: p = exp(s - 8), per-lane l accumulation only
        float p[4][4];
        #pragma unroll
        for (int ct = 0; ct < 4; ++ct)
            #pragma unroll
            for (int r = 0; r < 4; ++r) {
                p[ct][r] = __expf(sa[ct][r] - 8.0f);
                l_acc[r] += p[ct][r];
            }

        // P -> LDS (wave-private 16-row stripe; no barrier needed)
        #pragma unroll
        for (int ct = 0; ct < 4; ++ct)
            #pragma unroll
            for (int r = 0; r < 4; ++r)
                QPs[(16 * wave + quad * 4 + r) * LDK + ct * 16 + l15] = f2bf(p[ct][r]);

        short8 pa0 = *(const short8*)(QPs + (16 * wave + l15) * LDK + 0  + quad * 8);
        short8 pa1 = *(const short8*)(QPs + (16 * wave + l15) * LDK + 32 + quad * 8);
        #pragma unroll
        for (int dt = 0; dt < 4; ++dt) {
            const ushort_t* vrow = Vc + (dt * 16 + l15) * 64;
            short8 vb0 = *(const short8*)(vrow + ((quad ^ bx) << 3));
            short8 vb1 = *(const short8*)(vrow + (((quad + 4) ^ bx) << 3));
            O[dt] = __builtin_amdgcn_mfma_f32_16x16x32_bf16(pa0, vb0, O[dt], 0, 0, 0);
            O[dt] = __builtin_amdgcn_mfma_f32_16x16x32_bf16(pa1, vb1, O[dt], 0, 0, 0);
        }

        asm volatile("" ::: "memory");
        __builtin_amdgcn_s_barrier();   // protect buf before next overwrite
        cur ^= 1;
    }

    // one-time row-sum reduce across the 16 col-lanes
    float l_run[4];
    #pragma unroll
    for (int r = 0; r < 4; ++r) {
        float s = l_acc[r];
        s += __shfl_xor(s, 1);
        s += __shfl_xor(s, 2);
        s += __shfl_xor(s, 4);
        s += __shfl_xor(s, 8);
        l_run[r] = s;
    }

    if (pidx < 0) {
        // direct: normalize and write bf16
        #pragma unroll
        for (int r = 0; r < 4; ++r) {
            const float inv_l = 1.0f / l_run[r];
            const int t = t0 + 16 * wave + quad * 4 + r;
            #pragma unroll
            for (int dt = 0; dt < 4; ++dt)
                yb[(size_t)t * D_MODEL + h * HD + dt * 16 + l15] = f2bf(O[dt][r] * inv_l);
        }
    } else {
        // partial: unnormalized fp32 O + per-row l (fixed max => no m needed)
        float* __restrict__ Op = Opart + (size_t)pidx * 4096;
        #pragma unroll
        for (int r = 0; r < 4; ++r) {
            const int row = 16 * wave + quad * 4 + r;
            #pragma unroll
            for (int dt = 0; dt < 4; ++dt)
                Op[row * 64 + dt * 16 + l15] = O[dt][r];
            if (l15 == 0) Lpart[(size_t)pidx * 64 + row] = l_run[r];
        }
    }
}

// ---------------------------------------------------------------------------
// Kernel 2b: combine the two KV-chunk partials for qt in [16,32).
// Fixed max on both chunks => combined = (O0 + O1) / (l0 + l1).
// ---------------------------------------------------------------------------
__global__ __launch_bounds__(256) void attn_combine(
        const float* __restrict__ Opart, const float* __restrict__ Lpart,
        ushort_t* __restrict__ yb)
{
    const int qtp = blockIdx.x;          // qt = 16 + qtp
    const int h   = blockIdx.y;
    const int tid = threadIdx.x;
    const int row  = tid >> 2;           // 0..63
    const int dseg = (tid & 3) * 16;     // 0/16/32/48
    const int p0 = (h * 16 + qtp) * 2;

    const float l0 = Lpart[(size_t)p0 * 64 + row];
    const float l1 = Lpart[((size_t)p0 + 1) * 64 + row];
    const float inv = 1.0f / (l0 + l1);

    const float* O0 = Opart + (size_t)p0 * 4096 + row * 64 + dseg;
    const float* O1 = O0 + 4096;

    uint_t u[8];
    #pragma unroll
    for (int g = 0; g < 4; ++g) {
        float4 a = ((const float4*)O0)[g];
        float4 b = ((const float4*)O1)[g];
        u[g * 2 + 0] = pack2((a.x + b.x) * inv, (a.y + b.y) * inv);
        u[g * 2 + 1] = pack2((a.z + b.z) * inv, (a.w + b.w) * inv);
    }
    const int t = (16 + qtp) * 64 + row;
    uint4* dst = (uint4*)(yb + (size_t)t * D_MODEL + h * HD + dseg);
    dst[0] = make_uint4(u[0], u[1], u[2], u[3]);
    dst[1] = make_uint4(u[4], u[5], u[6], u[7]);
}

// ---------------------------------------------------------------------------
// Kernel 3: output projection, BM=64 BN=128 BK=64, grid (8,32) = 256 blocks
// = 1/CU. Same 2-phase double-buffered global_load_lds staging. fp32 out.
// ---------------------------------------------------------------------------
__global__ __launch_bounds__(256) void gemm_proj(
        const ushort_t* __restrict__ yb, const ushort_t* __restrict__ Wpb,
        float* __restrict__ out)
{
    const int row0 = blockIdx.y * 64;
    const int col0 = blockIdx.x * 128;

    __shared__ ushort_t As[2 * 64 * 64];
    __shared__ ushort_t Bs[2 * 128 * 64];

    const int tid = threadIdx.x;
    const int wave = tid >> 6, lane = tid & 63;
    const int wm = wave >> 1, wn = wave & 1;
    const int l15 = lane & 15, quad = lane >> 4;
    const int srow  = tid >> 3;
    const int sslot = (tid & 7) ^ (srow & 7);

    floatx4 acc[2][4];
    #pragma unroll
    for (int i = 0; i < 2; ++i)
        #pragma unroll
        for (int j = 0; j < 4; ++j)
            acc[i][j] = (floatx4){0.f, 0.f, 0.f, 0.f};

    auto stageAB = [&](int k0, int p) {
        ushort_t* Ap = As + p * 4096;
        ushort_t* Bp = Bs + p * 8192;
        #pragma unroll
        for (int c = 0; c < 2; ++c)
            gload16(yb + (size_t)(row0 + c * 32 + srow) * D_MODEL + k0 + sslot * 8,
                    Ap + c * 2048 + tid * 8);
        #pragma unroll
        for (int c = 0; c < 4; ++c)
            gload16(Wpb + (size_t)(col0 + c * 32 + srow) * D_MODEL + k0 + sslot * 8,
                    Bp + c * 2048 + tid * 8);
    };

    stageAB(0, 0);
    int cur = 0;
    for (int knext = 64; knext <= D_MODEL; knext += 64) {
        const bool haveNext = (knext < D_MODEL);
        if (haveNext) {
            stageAB(knext, cur ^ 1);
            asm volatile("s_waitcnt vmcnt(6)" ::: "memory");
        } else {
            asm volatile("s_waitcnt vmcnt(0)" ::: "memory");
        }
        __builtin_amdgcn_s_barrier();
        const ushort_t* Ac = As + cur * 4096;
        const ushort_t* Bc = Bs + cur * 8192;
        #pragma unroll
        for (int kh = 0; kh < 2; ++kh) {
            const int slot = ((kh * 4 + quad) ^ (l15 & 7)) << 3;
            short8 a[2], b[4];
            #pragma unroll
            for (int i = 0; i < 2; ++i)
                a[i] = *(const short8*)(Ac + (32 * wm + i * 16 + l15) * 64 + slot);
            #pragma unroll
            for (int j = 0; j < 4; ++j)
                b[j] = *(const short8*)(Bc + (64 * wn + j * 16 + l15) * 64 + slot);
            #pragma unroll
            for (int i = 0; i < 2; ++i)
                #pragma unroll
                for (int j = 0; j < 4; ++j)
                    acc[i][j] = __builtin_amdgcn_mfma_f32_16x16x32_bf16(a[i], b[j], acc[i][j], 0, 0, 0);
        }
        asm volatile("" ::: "memory");
        __builtin_amdgcn_s_barrier();
        cur ^= 1;
    }

    #pragma unroll
    for (int i = 0; i < 2; ++i)
        #pragma unroll
        for (int j = 0; j < 4; ++j) {
            const int t = row0 + 32 * wm + i * 16 + quad * 4;
            const int jj = col0 + 64 * wn + j * 16 + l15;
            #pragma unroll
            for (int r = 0; r < 4; ++r)
                out[(size_t)(t + r) * D_MODEL + jj] = acc[i][j][r];
        }
}

// ---------------------------------------------------------------------------
extern "C" void kernel_launch(void* const* d_in, const int* in_sizes, int n_in,
                              void* d_out, int out_size, void* d_ws, size_t ws_size,
                              hipStream_t stream) {
    (void)in_sizes; (void)n_in; (void)out_size; (void)ws_size;
    const float* x   = (const float*)d_in[0];
    const float* vi  = (const float*)d_in[1];
    const float* Wq  = (const float*)d_in[2];
    const float* Wk  = (const float*)d_in[3];
    const float* Wv  = (const float*)d_in[4];
    const float* Wp  = (const float*)d_in[5];
    const float* lam = (const float*)d_in[6];

    char* base = (char*)d_ws;                                  // 28 MiB used
    ushort_t* xb  = (ushort_t*)(base);                         // [ 0, 4) MiB (dead after gemm_qkv)
    ushort_t* wqb = (ushort_t*)(base + (size_t)4  * 1048576);  // [ 4, 6)  (dead after gemm_qkv)
    ushort_t* wkb = (ushort_t*)(base + (size_t)6  * 1048576);  // [ 6, 8)  (dead after gemm_qkv)
    ushort_t* wvb = (ushort_t*)(base + (size_t)8  * 1048576);  // [ 8,10)  (dead after gemm_qkv)
    ushort_t* wpb = (ushort_t*)(base + (size_t)10 * 1048576);  // [10,12)  (live until gemm_proj)
    ushort_t* qb  = (ushort_t*)(base + (size_t)12 * 1048576);  // [12,16)
    ushort_t* kb  = (ushort_t*)(base + (size_t)16 * 1048576);  // [16,20)
    ushort_t* vbt = (ushort_t*)(base + (size_t)20 * 1048576);  // [20,24)  [d][t]
    ushort_t* yb  = (ushort_t*)(base + (size_t)24 * 1048576);  // [24,28)
    // attn partials reuse [0, 8.2) MiB — dead xb/wqb/wkb/wvb space:
    float* Opart  = (float*)(base);                            // 512 * 4096 * 4B = 8 MiB
    float* Lpart  = (float*)(base + (size_t)8 * 1048576);      // 512 * 64 * 4B = 128 KiB
    float* out = (float*)d_out;

    to_bf16<<<dim3(786432 / 256), 256, 0, stream>>>(x, Wq, Wk, Wv, Wp, xb, wqb, wkb, wvb, wpb);
    gemm_qkv<<<dim3(8, 32, 3), 256, 0, stream>>>(xb, wqb, wkb, wvb, vi, lam, qb, kb, vbt);
    attn<<<dim3(48, 16), 256, 0, stream>>>(qb, kb, vbt, yb, Opart, Lpart);
    attn_combine<<<dim3(16, 16), 256, 0, stream>>>(Opart, Lpart, yb);
    gemm_proj<<<dim3(8, 32), 256, 0, stream>>>(yb, wpb, out);
}